// Round 2
// baseline (295763.940 us; speedup 1.0000x reference)
//
#include <hip/hip_runtime.h>
#include <hip/hip_cooperative_groups.h>

namespace cg = cooperative_groups;

constexpr int NB   = 64;     // batch
constexpr int NS   = 256;    // memory length S
constexpr int NT   = 500;    // time steps
constexpr int NMEL = 80;
constexpr int NE   = 512;    // memory dim E
constexpr int NP   = 256;    // prenet dim
constexpr int NA   = 1024;   // attention LSTM hidden
constexpr int ND   = 1024;   // decoder LSTM hidden
constexpr int NAD  = 128;    // attention dim
constexpr int ZC   = 4096;   // 4*hidden
constexpr int KA   = 1792;   // NP + NE + NA

constexpr int SMN  = 5280;   // LDS floats per block (21.1 KB -> 2 blocks/CU even @64KB acct)

// ---- workspace layout (floats); total ~20.6 MB ----
constexpr int OFF_KEYST = 0;                         // [64][128][256]
constexpr int OFF_FL    = OFF_KEYST + NB * NAD * NS; // [64][128][256]
constexpr int OFF_W2    = OFF_FL + NB * NAD * NS;    // [62][128]
constexpr int OFF_ZA    = OFF_W2 + 62 * NAD;         // [64][4096]
constexpr int OFF_ZD    = OFF_ZA + NB * ZC;          // [64][4096]
constexpr int OFF_HA    = OFF_ZD + NB * ZC;          // zero-block starts here
constexpr int OFF_CA    = OFF_HA + NB * NA;
constexpr int OFF_HD    = OFF_CA + NB * NA;
constexpr int OFF_CD    = OFF_HD + NB * ND;
constexpr int OFF_CTX   = OFF_CD + NB * ND;          // [2][64][512]
constexpr int OFF_WGL   = OFF_CTX + 2 * NB * NE;     // [64][256]
constexpr int OFF_WCU   = OFF_WGL + NB * NS;         // [64][256]
constexpr int OFF_P     = OFF_WCU + NB * NS;         // [2][64][256]
constexpr int OFF_PM1   = OFF_P + 2 * NB * NP;       // [64][256]
constexpr int ZERO_CNT  = OFF_P - OFF_HA;

constexpr long MEL_BASE   = 0;
constexpr long STOP_BASE  = (long)NB * NT * NMEL;      // 2,560,000
constexpr long ALIGN_BASE = STOP_BASE + (long)NB * NT; // 2,592,000

struct Params {
  const float *memory, *mel, *pw1, *pw2, *awx, *awh, *ab, *wq, *wm,
              *lconv, *wloc, *vatt, *dwx, *dwh, *db, *projw, *projb, *gatew, *gateb;
  float *out, *ws;
};

__device__ __forceinline__ float sigm(float x) { return 1.f / (1.f + __expf(-x)); }
__device__ __forceinline__ float tanh_t(float x) {
  x = fminf(fmaxf(x, -15.f), 15.f);
  const float a = __expf(2.f * x);
  return (a - 1.f) / (a + 1.f);
}

// prenet stage 1: pm1 = relu(mel[:, tnext, :] @ pw1), 8 WGs (wl 0..7), 8 b each
__device__ void do_s1(const Params& p, float* pm1, int tnext, int wl, int tid) {
  const int col = tid;
  for (int i = 0; i < 8; ++i) {
    const int b = wl * 8 + i;
    const float* mrow = p.mel + ((size_t)b * NT + tnext) * NMEL;
    float acc = 0.f;
    for (int k = 0; k < NMEL; ++k) acc += mrow[k] * p.pw1[k * NP + col];
    pm1[b * NP + col] = fmaxf(acc, 0.f);
  }
}

// prenet stage 2: pdst = relu(pm1 @ pw2), 16 WGs (wl 0..15), 4 b each
__device__ void do_s2(const Params& p, const float* pm1, float* pdst, int wl, int tid) {
  const int col = tid;
  for (int i = 0; i < 4; ++i) {
    const int b = wl * 4 + i;
    const float* pr = pm1 + b * NP;
    float acc = 0.f;
    for (int k = 0; k < NP; ++k) acc += pr[k] * p.pw2[k * NP + col];
    pdst[b * NP + col] = fmaxf(acc, 0.f);
  }
}

__device__ void pre_a(const Params& p, int wg, int tid) {
  float* ws = p.ws;
  const int gid = wg * 256 + tid;
  // zero recurrent state block (h_a,c_a,h_d,c_d,ctx[2],w,w_cum)
  for (int i = gid; i < ZERO_CNT; i += 512 * 256) (ws + OFF_HA)[i] = 0.f;
  // z buffers start at bias
  for (int i = gid; i < NB * ZC; i += 512 * 256) {
    ws[OFF_ZA + i] = p.ab[i & (ZC - 1)];
    ws[OFF_ZD + i] = p.db[i & (ZC - 1)];
  }
  // fused conv kernel W2[k2][ad] = sum_f lconv[k2][f] * wloc[f][ad], k2 = k*2+c
  for (int i = gid; i < 62 * NAD; i += 512 * 256) {
    const int k2 = i >> 7, ad = i & 127;
    float acc = 0.f;
    for (int f = 0; f < 32; ++f) acc += p.lconv[k2 * 32 + f] * p.wloc[f * NAD + ad];
    ws[OFF_W2 + i] = acc;
  }
  // keysT[b][ad][s] = sum_k memory[b][s][k] * wm[k][ad]; 8 WGs per b
  {
    const int b = wg >> 3, s0 = (wg & 7) * 32;
    const int sl = tid & 31, adg = tid >> 5;
    const float* mrow = p.memory + (size_t)(b * NS + s0 + sl) * NE;
    const float* wmb  = p.wm + adg * 16;
    float acc[16];
#pragma unroll
    for (int j = 0; j < 16; ++j) acc[j] = 0.f;
    for (int k = 0; k < NE; ++k) {
      const float mv = mrow[k];
      const float* wr = wmb + (size_t)k * NAD;
#pragma unroll
      for (int j = 0; j < 16; ++j) acc[j] += mv * wr[j];
    }
#pragma unroll
    for (int j = 0; j < 16; ++j)
      ws[OFF_KEYST + (b * NAD + adg * 16 + j) * NS + s0 + sl] = acc[j];
  }
  if (wg >= 496 && wg < 504) do_s1(p, ws + OFF_PM1, 0, wg - 496, tid);
}

__device__ void pre_b(const Params& p, int wg, int tid) {
  if (wg >= 128 && wg < 144) do_s2(p, p.ws + OFF_PM1, p.ws + OFF_P, wg - 128, tid);
}

__device__ void phase1(const Params& p, float* sm, int wg, int tid, int t) {
  float* ws = p.ws;
  if (wg < 176) {
    // attention-LSTM GEMM A(t): z_a += [p(t)|ctx(t-1)|h_a(t-1)] @ [awx;awh]
    if (t < NT) {
      const int cb = wg & 7, bs = (wg >> 3) & 1, kci = wg >> 4; // kci 0..10
      const int col0 = cb * 512, b0 = bs * 32, k0 = kci * 163;
      const int kc = min(163, KA - k0);
      const float* pcur = ws + OFF_P + (t & 1) * (NB * NP);
      const float* ctxp = ws + OFF_CTX + ((t + 1) & 1) * (NB * NE);
      const float* h_a  = ws + OFF_HA;
      for (int bb = 0; bb < 32; ++bb) {
        const int b = b0 + bb;
        for (int kk = tid; kk < kc; kk += 256) {
          const int k = k0 + kk;
          float v;
          if (k < NP)           v = pcur[b * NP + k];
          else if (k < NP + NE) v = ctxp[b * NE + (k - NP)];
          else                  v = h_a[b * NA + (k - NP - NE)];
          sm[bb * 164 + kk] = v;
        }
      }
      __syncthreads();
      const int bgrp = tid >> 6, cgrp = tid & 63;
      const int c = col0 + cgrp * 8;
      float acc[8][8];
#pragma unroll
      for (int i = 0; i < 8; ++i)
#pragma unroll
        for (int j = 0; j < 8; ++j) acc[i][j] = 0.f;
      const float* sxb = sm + bgrp * 8 * 164;
#pragma unroll 2
      for (int kk = 0; kk < kc; ++kk) {
        const int k = k0 + kk;
        const float* wr = (k < 768) ? (p.awx + (size_t)k * ZC + c)
                                    : (p.awh + (size_t)(k - 768) * ZC + c);
        const float4 w0 = *(const float4*)wr;
        const float4 w1 = *(const float4*)(wr + 4);
#pragma unroll
        for (int i = 0; i < 8; ++i) {
          const float x = sxb[i * 164 + kk];
          acc[i][0] += x * w0.x; acc[i][1] += x * w0.y;
          acc[i][2] += x * w0.z; acc[i][3] += x * w0.w;
          acc[i][4] += x * w1.x; acc[i][5] += x * w1.y;
          acc[i][6] += x * w1.z; acc[i][7] += x * w1.w;
        }
      }
      float* z_a = ws + OFF_ZA;
#pragma unroll
      for (int i = 0; i < 8; ++i) {
        const int b = b0 + bgrp * 8 + i;
#pragma unroll
        for (int j = 0; j < 8; ++j) atomicAdd(&z_a[b * ZC + c + j], acc[i][j]);
      }
      __syncthreads();
    }
  } else if (wg < 432) {
    // decoder-LSTM GEMM C(t-1): z_d += [h_a(t-1)|ctx(t-1)|h_d(t-2)] @ [dwx;dwh]
    if (t >= 1) {
      const int lw = wg - 176;
      const int cb = lw & 7, bs = (lw >> 3) & 1, kci = lw >> 4; // kci 0..15
      const int col0 = cb * 512, b0 = bs * 32, k0 = kci * 160;
      const int kc = 160;
      const float* ctxp = ws + OFF_CTX + ((t + 1) & 1) * (NB * NE);
      const float* h_a  = ws + OFF_HA;
      const float* h_d  = ws + OFF_HD;
      for (int bb = 0; bb < 32; ++bb) {
        const int b = b0 + bb;
        for (int kk = tid; kk < kc; kk += 256) {
          const int k = k0 + kk;
          float v;
          if (k < NA)           v = h_a[b * NA + k];
          else if (k < NA + NE) v = ctxp[b * NE + (k - NA)];
          else                  v = h_d[b * ND + (k - NA - NE)];
          sm[bb * 161 + kk] = v;
        }
      }
      __syncthreads();
      const int bgrp = tid >> 6, cgrp = tid & 63;
      const int c = col0 + cgrp * 8;
      float acc[8][8];
#pragma unroll
      for (int i = 0; i < 8; ++i)
#pragma unroll
        for (int j = 0; j < 8; ++j) acc[i][j] = 0.f;
      const float* sxb = sm + bgrp * 8 * 161;
#pragma unroll 2
      for (int kk = 0; kk < kc; ++kk) {
        const int k = k0 + kk;
        const float* wr = (k < 1536) ? (p.dwx + (size_t)k * ZC + c)
                                     : (p.dwh + (size_t)(k - 1536) * ZC + c);
        const float4 w0 = *(const float4*)wr;
        const float4 w1 = *(const float4*)(wr + 4);
#pragma unroll
        for (int i = 0; i < 8; ++i) {
          const float x = sxb[i * 161 + kk];
          acc[i][0] += x * w0.x; acc[i][1] += x * w0.y;
          acc[i][2] += x * w0.z; acc[i][3] += x * w0.w;
          acc[i][4] += x * w1.x; acc[i][5] += x * w1.y;
          acc[i][6] += x * w1.z; acc[i][7] += x * w1.w;
        }
      }
      float* z_d = ws + OFF_ZD;
#pragma unroll
      for (int i = 0; i < 8; ++i) {
        const int b = b0 + bgrp * 8 + i;
#pragma unroll
        for (int j = 0; j < 8; ++j) atomicAdd(&z_d[b * ZC + c + j], acc[i][j]);
      }
      __syncthreads();
    }
  } else if (wg < 496) {
    // location features fl(t)[b][ad][s] = keysT + conv([w,w_cum]) fused with w_loc
    if (t < NT) {
      const int b = wg - 432;
      float* chunk = sm;          // [62][64]
      float* wp0 = sm + 4000;     // 288 (15 pad + 256 + 17 pad)
      float* wp1 = sm + 4320;     // 288
      for (int i = tid; i < 288; i += 256) { wp0[i] = 0.f; wp1[i] = 0.f; }
      __syncthreads();
      wp0[15 + tid] = ws[OFF_WGL + b * NS + tid];
      wp1[15 + tid] = ws[OFF_WCU + b * NS + tid];
      __syncthreads();
      float x0[31], x1[31];
#pragma unroll
      for (int k = 0; k < 31; ++k) { x0[k] = wp0[tid + k]; x1[k] = wp1[tid + k]; }
      const float* kb = ws + OFF_KEYST + (b * NAD) * NS + tid;
      float* fb = ws + OFF_FL + (b * NAD) * NS + tid;
      const float* W2g = ws + OFF_W2;
      for (int ch = 0; ch < 2; ++ch) {
        for (int i = tid; i < 62 * 64; i += 256) {
          const int k2 = i >> 6, adl = i & 63;
          chunk[i] = W2g[k2 * NAD + ch * 64 + adl];
        }
        __syncthreads();
        for (int adl = 0; adl < 64; ++adl) {
          const int ad = ch * 64 + adl;
          float acc = kb[ad * NS];
#pragma unroll
          for (int k = 0; k < 31; ++k)
            acc = fmaf(x0[k], chunk[(2 * k) * 64 + adl],
                  fmaf(x1[k], chunk[(2 * k + 1) * 64 + adl], acc));
          fb[ad * NS] = acc;
        }
        __syncthreads();
      }
    }
  } else if (wg < 504) {
    if (t + 1 < NT) do_s1(p, ws + OFF_PM1, t + 1, wg - 496, tid);
  }
}

__device__ void phase2(const Params& p, float* sm, int wg, int tid, int t) {
  float* ws = p.ws;
  if (wg < 64) {
    // attention WG per b: LSTM-A update, query, energies, softmax, context
    if (t < NT) {
      const int b = wg;
      float* h_sh = sm;
      float* q_sh = sm + 1024;
      float* red  = sm + 1152;
      float* w_sh = sm + 1408;
      float* z_a  = ws + OFF_ZA;
      float* c_a  = ws + OFF_CA;
      float* h_a  = ws + OFF_HA;
#pragma unroll
      for (int j = 0; j < 4; ++j) {
        const int g = tid + j * 256;
        const float zi = z_a[b * ZC + g];
        const float zf = z_a[b * ZC + 1024 + g];
        const float zg = z_a[b * ZC + 2048 + g];
        const float zo = z_a[b * ZC + 3072 + g];
        const float cold = c_a[b * NA + g];
        const float iv = sigm(zi), fv = sigm(zf), gv = tanh_t(zg), ov = sigm(zo);
        const float c2 = fv * cold + iv * gv;
        const float h2 = ov * tanh_t(c2);
        c_a[b * NA + g] = c2;
        h_a[b * NA + g] = h2;
        h_sh[g] = h2;
        z_a[b * ZC + g]        = p.ab[g];
        z_a[b * ZC + 1024 + g] = p.ab[1024 + g];
        z_a[b * ZC + 2048 + g] = p.ab[2048 + g];
        z_a[b * ZC + 3072 + g] = p.ab[3072 + g];
      }
      __syncthreads();
      // query = h_a(t) @ wq ; split K over 2 halves
      {
        const int ad = tid & 127, kh = tid >> 7;
        float acc = 0.f;
        const float* wqp = p.wq + ad;
        for (int k = kh * 512; k < kh * 512 + 512; ++k) acc += h_sh[k] * wqp[(size_t)k * NAD];
        red[tid] = acc;
      }
      __syncthreads();
      if (tid < 128) q_sh[tid] = red[tid] + red[tid + 128];
      __syncthreads();
      // energies e[s] = sum_ad tanh(q + fl) * v
      float ev = 0.f;
      {
        const float* flp = ws + OFF_FL + (b * NAD) * NS + tid;
        for (int ad = 0; ad < NAD; ++ad)
          ev += tanh_t(q_sh[ad] + flp[ad * NS]) * p.vatt[ad];
      }
      // softmax over s
      red[tid] = ev; __syncthreads();
      for (int off = 128; off > 0; off >>= 1) {
        if (tid < off) red[tid] = fmaxf(red[tid], red[tid + off]);
        __syncthreads();
      }
      const float mx = red[0];
      __syncthreads();
      const float ex = __expf(ev - mx);
      red[tid] = ex; __syncthreads();
      for (int off = 128; off > 0; off >>= 1) {
        if (tid < off) red[tid] += red[tid + off];
        __syncthreads();
      }
      const float wv = ex / red[0];
      w_sh[tid] = wv;
      ws[OFF_WGL + b * NS + tid] = wv;
      ws[OFF_WCU + b * NS + tid] += wv;
      p.out[ALIGN_BASE + (size_t)b * NT * NS + (size_t)t * NS + tid] = wv;
      __syncthreads();
      // context = sum_s w[s] * memory[b][s][:]
      {
        float a0 = 0.f, a1 = 0.f;
        const float* mb = p.memory + (size_t)b * NS * NE;
        for (int ss = 0; ss < NS; ++ss) {
          const float wcur = w_sh[ss];
          a0 += wcur * mb[ss * NE + tid];
          a1 += wcur * mb[ss * NE + tid + 256];
        }
        float* cdst = ws + OFF_CTX + (t & 1) * (NB * NE) + b * NE;
        cdst[tid] = a0;
        cdst[tid + 256] = a1;
      }
    }
  } else if (wg < 128) {
    // decoder WG per b: LSTM-D update(t-1) + mel/stop projection(t-1)
    if (t >= 1) {
      const int b = wg - 64;
      const int tm1 = t - 1;
      float* h_sh = sm;
      float* red  = sm + 1024;
      float* z_d  = ws + OFF_ZD;
      float* c_d  = ws + OFF_CD;
      float* h_d  = ws + OFF_HD;
#pragma unroll
      for (int j = 0; j < 4; ++j) {
        const int g = tid + j * 256;
        const float zi = z_d[b * ZC + g];
        const float zf = z_d[b * ZC + 1024 + g];
        const float zg = z_d[b * ZC + 2048 + g];
        const float zo = z_d[b * ZC + 3072 + g];
        const float cold = c_d[b * ND + g];
        const float iv = sigm(zi), fv = sigm(zf), gv = tanh_t(zg), ov = sigm(zo);
        const float c2 = fv * cold + iv * gv;
        const float h2 = ov * tanh_t(c2);
        c_d[b * ND + g] = c2;
        h_d[b * ND + g] = h2;
        h_sh[g] = h2;
        z_d[b * ZC + g]        = p.db[g];
        z_d[b * ZC + 1024 + g] = p.db[1024 + g];
        z_d[b * ZC + 2048 + g] = p.db[2048 + g];
        z_d[b * ZC + 3072 + g] = p.db[3072 + g];
      }
      __syncthreads();
      const float* ctxp = ws + OFF_CTX + (tm1 & 1) * (NB * NE) + b * NE;
      // stop gate (256-way partial + tree)
      {
        float acc = 0.f;
        for (int k = tid; k < 1536; k += 256) {
          const float v = (k < 1024) ? h_sh[k] : ctxp[k - 1024];
          acc += v * p.gatew[k];
        }
        red[tid] = acc;
      }
      __syncthreads();
      for (int off = 128; off > 0; off >>= 1) {
        if (tid < off) red[tid] += red[tid + off];
        __syncthreads();
      }
      if (tid == 0) p.out[STOP_BASE + (size_t)b * NT + tm1] = sigm(red[0] + p.gateb[0]);
      __syncthreads();
      // mel projection: 3-way K split over 240 threads
      if (tid < 240) {
        const int m = tid % 80, kh = tid / 80;
        float acc = 0.f;
        for (int k = kh * 512; k < kh * 512 + 512; ++k) {
          const float v = (k < 1024) ? h_sh[k] : ctxp[k - 1024];
          acc += v * p.projw[(size_t)k * 80 + m];
        }
        red[kh * 80 + m] = acc;
      }
      __syncthreads();
      if (tid < 80) {
        const float mval = p.projb[tid] + red[tid] + red[80 + tid] + red[160 + tid];
        p.out[MEL_BASE + (size_t)b * NT * NMEL + (size_t)tm1 * NMEL + tid] = mval;
      }
    }
  } else if (wg < 144) {
    if (t + 1 < NT)
      do_s2(p, ws + OFF_PM1, ws + OFF_P + ((t + 1) & 1) * (NB * NP), wg - 128, tid);
  }
}

__global__ __launch_bounds__(256, 2) void taco_coop(Params p) {
  cg::grid_group grid = cg::this_grid();
  const int wg  = blockIdx.x;
  const int tid = threadIdx.x;
  __shared__ float sm[SMN];

  pre_a(p, wg, tid);
  grid.sync();
  pre_b(p, wg, tid);
  grid.sync();
  for (int t = 0; t <= NT; ++t) {
    phase1(p, sm, wg, tid, t);
    grid.sync();
    phase2(p, sm, wg, tid, t);
    grid.sync();
  }
}

// ---- non-cooperative fallback (same device logic, grid barrier = launch boundary) ----
__global__ __launch_bounds__(256, 2) void k_pre_a(Params p) { pre_a(p, blockIdx.x, threadIdx.x); }
__global__ __launch_bounds__(256, 2) void k_pre_b(Params p) { pre_b(p, blockIdx.x, threadIdx.x); }
__global__ __launch_bounds__(256, 2) void k_p1(Params p, int t) {
  __shared__ float sm[SMN];
  phase1(p, sm, blockIdx.x, threadIdx.x, t);
}
__global__ __launch_bounds__(256, 2) void k_p2(Params p, int t) {
  __shared__ float sm[SMN];
  phase2(p, sm, blockIdx.x, threadIdx.x, t);
}

extern "C" void kernel_launch(void* const* d_in, const int* in_sizes, int n_in,
                              void* d_out, int out_size, void* d_ws, size_t ws_size,
                              hipStream_t stream) {
  (void)in_sizes; (void)n_in; (void)out_size; (void)ws_size; // needs ~20.6 MB ws
  Params prm;
  prm.memory = (const float*)d_in[0];
  prm.mel    = (const float*)d_in[1];
  prm.pw1    = (const float*)d_in[2];
  prm.pw2    = (const float*)d_in[3];
  prm.awx    = (const float*)d_in[4];
  prm.awh    = (const float*)d_in[5];
  prm.ab     = (const float*)d_in[6];
  prm.wq     = (const float*)d_in[7];
  prm.wm     = (const float*)d_in[8];
  prm.lconv  = (const float*)d_in[9];
  prm.wloc   = (const float*)d_in[10];
  prm.vatt   = (const float*)d_in[11];
  prm.dwx    = (const float*)d_in[12];
  prm.dwh    = (const float*)d_in[13];
  prm.db     = (const float*)d_in[14];
  prm.projw  = (const float*)d_in[15];
  prm.projb  = (const float*)d_in[16];
  prm.gatew  = (const float*)d_in[17];
  prm.gateb  = (const float*)d_in[18];
  prm.out = (float*)d_out;
  prm.ws  = (float*)d_ws;

  void* args[] = { &prm };
  hipError_t err = hipLaunchCooperativeKernel((void*)taco_coop, dim3(512), dim3(256),
                                              args, 0, stream);
  if (err != hipSuccess) {
    // cooperative launch rejected -> per-phase launches (grid barrier at launch boundary)
    k_pre_a<<<dim3(512), dim3(256), 0, stream>>>(prm);
    k_pre_b<<<dim3(512), dim3(256), 0, stream>>>(prm);
    for (int t = 0; t <= NT; ++t) {
      k_p1<<<dim3(512), dim3(256), 0, stream>>>(prm, t);
      k_p2<<<dim3(512), dim3(256), 0, stream>>>(prm, t);
    }
  }
}

// Round 3
// 238099.146 us; speedup vs baseline: 1.2422x; 1.2422x over previous
//
#include <hip/hip_runtime.h>
#include <hip/hip_cooperative_groups.h>

namespace cg = cooperative_groups;

constexpr int NB   = 64;     // batch
constexpr int NS   = 256;    // memory length S
constexpr int NT   = 500;    // time steps
constexpr int NMEL = 80;
constexpr int NE   = 512;    // memory dim E
constexpr int NP   = 256;    // prenet dim
constexpr int NA   = 1024;   // attention LSTM hidden
constexpr int ND   = 1024;   // decoder LSTM hidden
constexpr int NAD  = 128;    // attention dim
constexpr int ZC   = 4096;   // 4*hidden
constexpr int KA   = 1792;   // NP + NE + NA
constexpr int NKA  = 11;     // A k-chunks (163 each)
constexpr int NKD  = 16;     // D k-chunks (160 each)

constexpr int SMN  = 5280;   // LDS floats per block (21.1 KB; known-good for coop 512 blocks)

// ---- workspace layout (floats) ----
// base (atomic-compatible) region: ~20.6 MB
constexpr int OFF_KEYST = 0;                         // [64][128][256]
constexpr int OFF_FL    = OFF_KEYST + NB * NAD * NS; // [64][128][256]
constexpr int OFF_W2    = OFF_FL + NB * NAD * NS;    // [62][128]
constexpr int OFF_ZA    = OFF_W2 + 62 * NAD;         // [64][4096] (atomic mode only)
constexpr int OFF_ZD    = OFF_ZA + NB * ZC;          // [64][4096] (atomic mode only)
constexpr int OFF_HA    = OFF_ZD + NB * ZC;          // zero-block starts here
constexpr int OFF_CA    = OFF_HA + NB * NA;
constexpr int OFF_HD    = OFF_CA + NB * NA;
constexpr int OFF_CD    = OFF_HD + NB * ND;
constexpr int OFF_CTX   = OFF_CD + NB * ND;          // [2][64][512]
constexpr int OFF_WGL   = OFF_CTX + 2 * NB * NE;     // [64][256]
constexpr int OFF_WCU   = OFF_WGL + NB * NS;         // [64][256]
constexpr int OFF_P     = OFF_WCU + NB * NS;         // [2][64][256]
constexpr int OFF_PM1   = OFF_P + 2 * NB * NP;       // [64][256]
constexpr int WS_BASE   = OFF_PM1 + NB * NP;         // 5,136,128 floats
constexpr int ZERO_CNT  = OFF_P - OFF_HA;
// partial-sum extension (no atomics): +27.6 MB
constexpr int OFF_ZAP   = WS_BASE;                    // [11][64][4096]
constexpr int OFF_ZDP   = OFF_ZAP + NKA * NB * ZC;    // [16][64][4096]
constexpr long WS_FULL  = (long)OFF_ZDP + (long)NKD * NB * ZC; // 12,214,016 floats

constexpr long MEL_BASE   = 0;
constexpr long STOP_BASE  = (long)NB * NT * NMEL;      // 2,560,000
constexpr long ALIGN_BASE = STOP_BASE + (long)NB * NT; // 2,592,000

struct Params {
  const float *memory, *mel, *pw1, *pw2, *awx, *awh, *ab, *wq, *wm,
              *lconv, *wloc, *vatt, *dwx, *dwh, *db, *projw, *projb, *gatew, *gateb;
  float *out, *ws;
};

__device__ __forceinline__ float sigm(float x) { return 1.f / (1.f + __expf(-x)); }
__device__ __forceinline__ float tanh_t(float x) {
  x = fminf(fmaxf(x, -15.f), 15.f);
  const float a = __expf(2.f * x);
  return (a - 1.f) / (a + 1.f);
}

// prenet stage 1: pm1 = relu(mel[:, tnext, :] @ pw1), 8 WGs (wl 0..7), 8 b each
__device__ void do_s1(const Params& p, float* pm1, int tnext, int wl, int tid) {
  const int col = tid;
  for (int i = 0; i < 8; ++i) {
    const int b = wl * 8 + i;
    const float* mrow = p.mel + ((size_t)b * NT + tnext) * NMEL;
    float acc = 0.f;
    for (int k = 0; k < NMEL; ++k) acc += mrow[k] * p.pw1[k * NP + col];
    pm1[b * NP + col] = fmaxf(acc, 0.f);
  }
}

// prenet stage 2: pdst = relu(pm1 @ pw2), 16 WGs (wl 0..15), 4 b each
__device__ void do_s2(const Params& p, const float* pm1, float* pdst, int wl, int tid) {
  const int col = tid;
  for (int i = 0; i < 4; ++i) {
    const int b = wl * 4 + i;
    const float* pr = pm1 + b * NP;
    float acc = 0.f;
    for (int k = 0; k < NP; ++k) acc += pr[k] * p.pw2[k * NP + col];
    pdst[b * NP + col] = fmaxf(acc, 0.f);
  }
}

template<bool PART>
__device__ void pre_a(const Params& p, int wg, int tid) {
  float* ws = p.ws;
  const int gid = wg * 256 + tid;
  // zero recurrent state block (h_a,c_a,h_d,c_d,ctx[2],w,w_cum)
  for (int i = gid; i < ZERO_CNT; i += 512 * 256) (ws + OFF_HA)[i] = 0.f;
  if (!PART) {
    // atomic mode: z buffers start at bias
    for (int i = gid; i < NB * ZC; i += 512 * 256) {
      ws[OFF_ZA + i] = p.ab[i & (ZC - 1)];
      ws[OFF_ZD + i] = p.db[i & (ZC - 1)];
    }
  }
  // fused conv kernel W2[k2][ad] = sum_f lconv[k2][f] * wloc[f][ad], k2 = k*2+c
  for (int i = gid; i < 62 * NAD; i += 512 * 256) {
    const int k2 = i >> 7, ad = i & 127;
    float acc = 0.f;
    for (int f = 0; f < 32; ++f) acc += p.lconv[k2 * 32 + f] * p.wloc[f * NAD + ad];
    ws[OFF_W2 + i] = acc;
  }
  // keysT[b][ad][s] = sum_k memory[b][s][k] * wm[k][ad]; 8 WGs per b
  {
    const int b = wg >> 3, s0 = (wg & 7) * 32;
    const int sl = tid & 31, adg = tid >> 5;
    const float* mrow = p.memory + (size_t)(b * NS + s0 + sl) * NE;
    const float* wmb  = p.wm + adg * 16;
    float acc[16];
#pragma unroll
    for (int j = 0; j < 16; ++j) acc[j] = 0.f;
    for (int k = 0; k < NE; ++k) {
      const float mv = mrow[k];
      const float* wr = wmb + (size_t)k * NAD;
#pragma unroll
      for (int j = 0; j < 16; ++j) acc[j] += mv * wr[j];
    }
#pragma unroll
    for (int j = 0; j < 16; ++j)
      ws[OFF_KEYST + (b * NAD + adg * 16 + j) * NS + s0 + sl] = acc[j];
  }
  if (wg >= 496 && wg < 504) do_s1(p, ws + OFF_PM1, 0, wg - 496, tid);
}

__device__ void pre_b(const Params& p, int wg, int tid) {
  if (wg >= 128 && wg < 144) do_s2(p, p.ws + OFF_PM1, p.ws + OFF_P, wg - 128, tid);
}

template<bool PART>
__device__ void phase1(const Params& p, float* sm, int wg, int tid, int t) {
  float* ws = p.ws;
  if (wg < 176) {
    // attention-LSTM GEMM A(t): [p(t)|ctx(t-1)|h_a(t-1)] @ [awx;awh]
    if (t < NT) {
      const int cb = wg & 7, bs = (wg >> 3) & 1, kci = wg >> 4; // kci 0..10
      const int col0 = cb * 512, b0 = bs * 32, k0 = kci * 163;
      const int kc = min(163, KA - k0);
      const float* pcur = ws + OFF_P + (t & 1) * (NB * NP);
      const float* ctxp = ws + OFF_CTX + ((t + 1) & 1) * (NB * NE);
      const float* h_a  = ws + OFF_HA;
      for (int bb = 0; bb < 32; ++bb) {
        const int b = b0 + bb;
        for (int kk = tid; kk < kc; kk += 256) {
          const int k = k0 + kk;
          float v;
          if (k < NP)           v = pcur[b * NP + k];
          else if (k < NP + NE) v = ctxp[b * NE + (k - NP)];
          else                  v = h_a[b * NA + (k - NP - NE)];
          sm[bb * 164 + kk] = v;
        }
      }
      __syncthreads();
      const int bgrp = tid >> 6, cgrp = tid & 63;
      const int c = col0 + cgrp * 8;
      float acc[8][8];
#pragma unroll
      for (int i = 0; i < 8; ++i)
#pragma unroll
        for (int j = 0; j < 8; ++j) acc[i][j] = 0.f;
      const float* sxb = sm + bgrp * 8 * 164;
#pragma unroll 2
      for (int kk = 0; kk < kc; ++kk) {
        const int k = k0 + kk;
        const float* wr = (k < 768) ? (p.awx + (size_t)k * ZC + c)
                                    : (p.awh + (size_t)(k - 768) * ZC + c);
        const float4 w0 = *(const float4*)wr;
        const float4 w1 = *(const float4*)(wr + 4);
#pragma unroll
        for (int i = 0; i < 8; ++i) {
          const float x = sxb[i * 164 + kk];
          acc[i][0] += x * w0.x; acc[i][1] += x * w0.y;
          acc[i][2] += x * w0.z; acc[i][3] += x * w0.w;
          acc[i][4] += x * w1.x; acc[i][5] += x * w1.y;
          acc[i][6] += x * w1.z; acc[i][7] += x * w1.w;
        }
      }
      if (PART) {
        float* zap = ws + OFF_ZAP;
#pragma unroll
        for (int i = 0; i < 8; ++i) {
          const int b = b0 + bgrp * 8 + i;
          float* dst = zap + (size_t)(kci * NB + b) * ZC + c;
          *(float4*)dst       = make_float4(acc[i][0], acc[i][1], acc[i][2], acc[i][3]);
          *(float4*)(dst + 4) = make_float4(acc[i][4], acc[i][5], acc[i][6], acc[i][7]);
        }
      } else {
        float* z_a = ws + OFF_ZA;
#pragma unroll
        for (int i = 0; i < 8; ++i) {
          const int b = b0 + bgrp * 8 + i;
#pragma unroll
          for (int j = 0; j < 8; ++j) atomicAdd(&z_a[b * ZC + c + j], acc[i][j]);
        }
      }
      __syncthreads();
    }
  } else if (wg < 432) {
    // decoder-LSTM GEMM C(t-1): [h_a(t-1)|ctx(t-1)|h_d(t-2)] @ [dwx;dwh]
    if (t >= 1) {
      const int lw = wg - 176;
      const int cb = lw & 7, bs = (lw >> 3) & 1, kci = lw >> 4; // kci 0..15
      const int col0 = cb * 512, b0 = bs * 32, k0 = kci * 160;
      const int kc = 160;
      const float* ctxp = ws + OFF_CTX + ((t + 1) & 1) * (NB * NE);
      const float* h_a  = ws + OFF_HA;
      const float* h_d  = ws + OFF_HD;
      for (int bb = 0; bb < 32; ++bb) {
        const int b = b0 + bb;
        for (int kk = tid; kk < kc; kk += 256) {
          const int k = k0 + kk;
          float v;
          if (k < NA)           v = h_a[b * NA + k];
          else if (k < NA + NE) v = ctxp[b * NE + (k - NA)];
          else                  v = h_d[b * ND + (k - NA - NE)];
          sm[bb * 161 + kk] = v;
        }
      }
      __syncthreads();
      const int bgrp = tid >> 6, cgrp = tid & 63;
      const int c = col0 + cgrp * 8;
      float acc[8][8];
#pragma unroll
      for (int i = 0; i < 8; ++i)
#pragma unroll
        for (int j = 0; j < 8; ++j) acc[i][j] = 0.f;
      const float* sxb = sm + bgrp * 8 * 161;
#pragma unroll 2
      for (int kk = 0; kk < kc; ++kk) {
        const int k = k0 + kk;
        const float* wr = (k < 1536) ? (p.dwx + (size_t)k * ZC + c)
                                     : (p.dwh + (size_t)(k - 1536) * ZC + c);
        const float4 w0 = *(const float4*)wr;
        const float4 w1 = *(const float4*)(wr + 4);
#pragma unroll
        for (int i = 0; i < 8; ++i) {
          const float x = sxb[i * 161 + kk];
          acc[i][0] += x * w0.x; acc[i][1] += x * w0.y;
          acc[i][2] += x * w0.z; acc[i][3] += x * w0.w;
          acc[i][4] += x * w1.x; acc[i][5] += x * w1.y;
          acc[i][6] += x * w1.z; acc[i][7] += x * w1.w;
        }
      }
      if (PART) {
        float* zdp = ws + OFF_ZDP;
#pragma unroll
        for (int i = 0; i < 8; ++i) {
          const int b = b0 + bgrp * 8 + i;
          float* dst = zdp + (size_t)(kci * NB + b) * ZC + c;
          *(float4*)dst       = make_float4(acc[i][0], acc[i][1], acc[i][2], acc[i][3]);
          *(float4*)(dst + 4) = make_float4(acc[i][4], acc[i][5], acc[i][6], acc[i][7]);
        }
      } else {
        float* z_d = ws + OFF_ZD;
#pragma unroll
        for (int i = 0; i < 8; ++i) {
          const int b = b0 + bgrp * 8 + i;
#pragma unroll
          for (int j = 0; j < 8; ++j) atomicAdd(&z_d[b * ZC + c + j], acc[i][j]);
        }
      }
      __syncthreads();
    }
  } else if (wg < 496) {
    // location features fl(t)[b][ad][s] = keysT + conv([w,w_cum]) fused with w_loc
    if (t < NT) {
      const int b = wg - 432;
      float* chunk = sm;          // [62][64]
      float* wp0 = sm + 4000;     // 288 (15 pad + 256 + 17 pad)
      float* wp1 = sm + 4320;     // 288
      for (int i = tid; i < 288; i += 256) { wp0[i] = 0.f; wp1[i] = 0.f; }
      __syncthreads();
      wp0[15 + tid] = ws[OFF_WGL + b * NS + tid];
      wp1[15 + tid] = ws[OFF_WCU + b * NS + tid];
      __syncthreads();
      float x0[31], x1[31];
#pragma unroll
      for (int k = 0; k < 31; ++k) { x0[k] = wp0[tid + k]; x1[k] = wp1[tid + k]; }
      const float* kb = ws + OFF_KEYST + (b * NAD) * NS + tid;
      float* fb = ws + OFF_FL + (b * NAD) * NS + tid;
      const float* W2g = ws + OFF_W2;
      for (int ch = 0; ch < 2; ++ch) {
        for (int i = tid; i < 62 * 64; i += 256) {
          const int k2 = i >> 6, adl = i & 63;
          chunk[i] = W2g[k2 * NAD + ch * 64 + adl];
        }
        __syncthreads();
        for (int adl = 0; adl < 64; ++adl) {
          const int ad = ch * 64 + adl;
          float acc = kb[ad * NS];
#pragma unroll
          for (int k = 0; k < 31; ++k)
            acc = fmaf(x0[k], chunk[(2 * k) * 64 + adl],
                  fmaf(x1[k], chunk[(2 * k + 1) * 64 + adl], acc));
          fb[ad * NS] = acc;
        }
        __syncthreads();
      }
    }
  } else if (wg < 504) {
    if (t + 1 < NT) do_s1(p, ws + OFF_PM1, t + 1, wg - 496, tid);
  }
}

template<bool PART>
__device__ void phase2(const Params& p, float* sm, int wg, int tid, int t) {
  float* ws = p.ws;
  if (wg < 64) {
    // attention WG per b: LSTM-A update, query, energies, softmax, context
    if (t < NT) {
      const int b = wg;
      float* h_sh = sm;
      float* q_sh = sm + 1024;
      float* red  = sm + 1152;
      float* w_sh = sm + 1408;
      float* c_a  = ws + OFF_CA;
      float* h_a  = ws + OFF_HA;
#pragma unroll
      for (int j = 0; j < 4; ++j) {
        const int g = tid + j * 256;
        float zi, zf, zg, zo;
        if (PART) {
          zi = p.ab[g]; zf = p.ab[1024 + g]; zg = p.ab[2048 + g]; zo = p.ab[3072 + g];
          const float* zap = ws + OFF_ZAP + (size_t)b * ZC;
#pragma unroll 1
          for (int kci = 0; kci < NKA; ++kci) {
            const float* zp = zap + (size_t)kci * NB * ZC;
            zi += zp[g]; zf += zp[1024 + g]; zg += zp[2048 + g]; zo += zp[3072 + g];
          }
        } else {
          float* z_a = ws + OFF_ZA;
          zi = z_a[b * ZC + g];
          zf = z_a[b * ZC + 1024 + g];
          zg = z_a[b * ZC + 2048 + g];
          zo = z_a[b * ZC + 3072 + g];
          z_a[b * ZC + g]        = p.ab[g];
          z_a[b * ZC + 1024 + g] = p.ab[1024 + g];
          z_a[b * ZC + 2048 + g] = p.ab[2048 + g];
          z_a[b * ZC + 3072 + g] = p.ab[3072 + g];
        }
        const float cold = c_a[b * NA + g];
        const float iv = sigm(zi), fv = sigm(zf), gv = tanh_t(zg), ov = sigm(zo);
        const float c2 = fv * cold + iv * gv;
        const float h2 = ov * tanh_t(c2);
        c_a[b * NA + g] = c2;
        h_a[b * NA + g] = h2;
        h_sh[g] = h2;
      }
      __syncthreads();
      // query = h_a(t) @ wq ; split K over 2 halves
      {
        const int ad = tid & 127, kh = tid >> 7;
        float acc = 0.f;
        const float* wqp = p.wq + ad;
        for (int k = kh * 512; k < kh * 512 + 512; ++k) acc += h_sh[k] * wqp[(size_t)k * NAD];
        red[tid] = acc;
      }
      __syncthreads();
      if (tid < 128) q_sh[tid] = red[tid] + red[tid + 128];
      __syncthreads();
      // energies e[s] = sum_ad tanh(q + fl) * v
      float ev = 0.f;
      {
        const float* flp = ws + OFF_FL + (b * NAD) * NS + tid;
        for (int ad = 0; ad < NAD; ++ad)
          ev += tanh_t(q_sh[ad] + flp[ad * NS]) * p.vatt[ad];
      }
      // softmax over s
      red[tid] = ev; __syncthreads();
      for (int off = 128; off > 0; off >>= 1) {
        if (tid < off) red[tid] = fmaxf(red[tid], red[tid + off]);
        __syncthreads();
      }
      const float mx = red[0];
      __syncthreads();
      const float ex = __expf(ev - mx);
      red[tid] = ex; __syncthreads();
      for (int off = 128; off > 0; off >>= 1) {
        if (tid < off) red[tid] += red[tid + off];
        __syncthreads();
      }
      const float wv = ex / red[0];
      w_sh[tid] = wv;
      ws[OFF_WGL + b * NS + tid] = wv;
      ws[OFF_WCU + b * NS + tid] += wv;
      p.out[ALIGN_BASE + (size_t)b * NT * NS + (size_t)t * NS + tid] = wv;
      __syncthreads();
      // context = sum_s w[s] * memory[b][s][:]
      {
        float a0 = 0.f, a1 = 0.f;
        const float* mb = p.memory + (size_t)b * NS * NE;
        for (int ss = 0; ss < NS; ++ss) {
          const float wcur = w_sh[ss];
          a0 += wcur * mb[ss * NE + tid];
          a1 += wcur * mb[ss * NE + tid + 256];
        }
        float* cdst = ws + OFF_CTX + (t & 1) * (NB * NE) + b * NE;
        cdst[tid] = a0;
        cdst[tid + 256] = a1;
      }
    }
  } else if (wg < 128) {
    // decoder WG per b: LSTM-D update(t-1) + mel/stop projection(t-1)
    if (t >= 1) {
      const int b = wg - 64;
      const int tm1 = t - 1;
      float* h_sh = sm;
      float* red  = sm + 1024;
      float* c_d  = ws + OFF_CD;
      float* h_d  = ws + OFF_HD;
#pragma unroll
      for (int j = 0; j < 4; ++j) {
        const int g = tid + j * 256;
        float zi, zf, zg, zo;
        if (PART) {
          zi = p.db[g]; zf = p.db[1024 + g]; zg = p.db[2048 + g]; zo = p.db[3072 + g];
          const float* zdp = ws + OFF_ZDP + (size_t)b * ZC;
#pragma unroll 1
          for (int kci = 0; kci < NKD; ++kci) {
            const float* zp = zdp + (size_t)kci * NB * ZC;
            zi += zp[g]; zf += zp[1024 + g]; zg += zp[2048 + g]; zo += zp[3072 + g];
          }
        } else {
          float* z_d = ws + OFF_ZD;
          zi = z_d[b * ZC + g];
          zf = z_d[b * ZC + 1024 + g];
          zg = z_d[b * ZC + 2048 + g];
          zo = z_d[b * ZC + 3072 + g];
          z_d[b * ZC + g]        = p.db[g];
          z_d[b * ZC + 1024 + g] = p.db[1024 + g];
          z_d[b * ZC + 2048 + g] = p.db[2048 + g];
          z_d[b * ZC + 3072 + g] = p.db[3072 + g];
        }
        const float cold = c_d[b * ND + g];
        const float iv = sigm(zi), fv = sigm(zf), gv = tanh_t(zg), ov = sigm(zo);
        const float c2 = fv * cold + iv * gv;
        const float h2 = ov * tanh_t(c2);
        c_d[b * ND + g] = c2;
        h_d[b * ND + g] = h2;
        h_sh[g] = h2;
      }
      __syncthreads();
      const float* ctxp = ws + OFF_CTX + (tm1 & 1) * (NB * NE) + b * NE;
      // stop gate (256-way partial + tree)
      {
        float acc = 0.f;
        for (int k = tid; k < 1536; k += 256) {
          const float v = (k < 1024) ? h_sh[k] : ctxp[k - 1024];
          acc += v * p.gatew[k];
        }
        red[tid] = acc;
      }
      __syncthreads();
      for (int off = 128; off > 0; off >>= 1) {
        if (tid < off) red[tid] += red[tid + off];
        __syncthreads();
      }
      if (tid == 0) p.out[STOP_BASE + (size_t)b * NT + tm1] = sigm(red[0] + p.gateb[0]);
      __syncthreads();
      // mel projection: 3-way K split over 240 threads
      if (tid < 240) {
        const int m = tid % 80, kh = tid / 80;
        float acc = 0.f;
        for (int k = kh * 512; k < kh * 512 + 512; ++k) {
          const float v = (k < 1024) ? h_sh[k] : ctxp[k - 1024];
          acc += v * p.projw[(size_t)k * 80 + m];
        }
        red[kh * 80 + m] = acc;
      }
      __syncthreads();
      if (tid < 80) {
        const float mval = p.projb[tid] + red[tid] + red[80 + tid] + red[160 + tid];
        p.out[MEL_BASE + (size_t)b * NT * NMEL + (size_t)tm1 * NMEL + tid] = mval;
      }
    }
  } else if (wg < 144) {
    if (t + 1 < NT)
      do_s2(p, ws + OFF_PM1, ws + OFF_P + ((t + 1) & 1) * (NB * NP), wg - 128, tid);
  }
}

template<bool PART>
__global__ __launch_bounds__(256, 2) void taco_coop(Params p) {
  cg::grid_group grid = cg::this_grid();
  const int wg  = blockIdx.x;
  const int tid = threadIdx.x;
  __shared__ float sm[SMN];

  pre_a<PART>(p, wg, tid);
  grid.sync();
  pre_b(p, wg, tid);
  grid.sync();
  for (int t = 0; t <= NT; ++t) {
    phase1<PART>(p, sm, wg, tid, t);
    grid.sync();
    phase2<PART>(p, sm, wg, tid, t);
    grid.sync();
  }
}

// ---- non-cooperative fallback (atomic variant; grid barrier = launch boundary) ----
__global__ __launch_bounds__(256, 2) void k_pre_a(Params p) { pre_a<false>(p, blockIdx.x, threadIdx.x); }
__global__ __launch_bounds__(256, 2) void k_pre_b(Params p) { pre_b(p, blockIdx.x, threadIdx.x); }
__global__ __launch_bounds__(256, 2) void k_p1(Params p, int t) {
  __shared__ float sm[SMN];
  phase1<false>(p, sm, blockIdx.x, threadIdx.x, t);
}
__global__ __launch_bounds__(256, 2) void k_p2(Params p, int t) {
  __shared__ float sm[SMN];
  phase2<false>(p, sm, blockIdx.x, threadIdx.x, t);
}

extern "C" void kernel_launch(void* const* d_in, const int* in_sizes, int n_in,
                              void* d_out, int out_size, void* d_ws, size_t ws_size,
                              hipStream_t stream) {
  (void)in_sizes; (void)n_in; (void)out_size;
  Params prm;
  prm.memory = (const float*)d_in[0];
  prm.mel    = (const float*)d_in[1];
  prm.pw1    = (const float*)d_in[2];
  prm.pw2    = (const float*)d_in[3];
  prm.awx    = (const float*)d_in[4];
  prm.awh    = (const float*)d_in[5];
  prm.ab     = (const float*)d_in[6];
  prm.wq     = (const float*)d_in[7];
  prm.wm     = (const float*)d_in[8];
  prm.lconv  = (const float*)d_in[9];
  prm.wloc   = (const float*)d_in[10];
  prm.vatt   = (const float*)d_in[11];
  prm.dwx    = (const float*)d_in[12];
  prm.dwh    = (const float*)d_in[13];
  prm.db     = (const float*)d_in[14];
  prm.projw  = (const float*)d_in[15];
  prm.projb  = (const float*)d_in[16];
  prm.gatew  = (const float*)d_in[17];
  prm.gateb  = (const float*)d_in[18];
  prm.out = (float*)d_out;
  prm.ws  = (float*)d_ws;

  const bool part = ws_size >= (size_t)WS_FULL * sizeof(float);
  void* args[] = { &prm };
  hipError_t err;
  if (part) {
    err = hipLaunchCooperativeKernel((void*)taco_coop<true>, dim3(512), dim3(256),
                                     args, 0, stream);
  } else {
    err = hipLaunchCooperativeKernel((void*)taco_coop<false>, dim3(512), dim3(256),
                                     args, 0, stream);
  }
  if (err != hipSuccess) {
    // cooperative launch rejected -> per-phase launches (atomic variant)
    k_pre_a<<<dim3(512), dim3(256), 0, stream>>>(prm);
    k_pre_b<<<dim3(512), dim3(256), 0, stream>>>(prm);
    for (int t = 0; t <= NT; ++t) {
      k_p1<<<dim3(512), dim3(256), 0, stream>>>(prm, t);
      k_p2<<<dim3(512), dim3(256), 0, stream>>>(prm, t);
    }
  }
}

// Round 4
// 216164.893 us; speedup vs baseline: 1.3682x; 1.1015x over previous
//
#include <hip/hip_runtime.h>
#include <hip/hip_cooperative_groups.h>

namespace cg = cooperative_groups;

constexpr int NB   = 64;     // batch
constexpr int NS   = 256;    // memory length S
constexpr int NT   = 500;    // time steps
constexpr int NMEL = 80;
constexpr int NE   = 512;    // memory dim E
constexpr int NP   = 256;    // prenet dim
constexpr int NA   = 1024;   // attention LSTM hidden
constexpr int ND   = 1024;   // decoder LSTM hidden
constexpr int NAD  = 128;    // attention dim
constexpr int ZC   = 4096;   // 4*hidden
constexpr int KA   = 1792;   // NP + NE + NA
constexpr int KD   = 2560;   // NA + NE + ND
constexpr int NKA  = 11;     // legacy f32 path A k-chunks
constexpr int NKD  = 16;     // legacy f32 path D k-chunks
constexpr int G    = 512;    // grid blocks

constexpr int SMN  = 5280;   // LDS floats (21.1 KB -> 2 blocks/CU, coop-safe)

// ---- workspace layout (floats) ----
constexpr int OFF_KEYST = 0;                         // [64][128][256]
constexpr int OFF_FL    = OFF_KEYST + NB * NAD * NS; // [64][128][256]
constexpr int OFF_W2    = OFF_FL + NB * NAD * NS;    // [62][128]
constexpr int OFF_ZA    = OFF_W2 + 62 * NAD;         // atomic mode only
constexpr int OFF_ZD    = OFF_ZA + NB * ZC;          // atomic mode only
constexpr int OFF_HA    = OFF_ZD + NB * ZC;          // zero-block starts here
constexpr int OFF_CA    = OFF_HA + NB * NA;
constexpr int OFF_HD    = OFF_CA + NB * NA;
constexpr int OFF_CD    = OFF_HD + NB * ND;
constexpr int OFF_CTX   = OFF_CD + NB * ND;          // [2][64][512]
constexpr int OFF_WGL   = OFF_CTX + 2 * NB * NE;     // [64][256]
constexpr int OFF_WCU   = OFF_WGL + NB * NS;         // [64][256]
constexpr int OFF_P     = OFF_WCU + NB * NS;         // [2][64][256]
constexpr int OFF_PM1   = OFF_P + 2 * NB * NP;       // [64][256]
constexpr int WS_BASE   = OFF_PM1 + NB * NP;         // 5,136,128 floats
constexpr int ZERO_CNT  = OFF_P - OFF_HA;
// legacy f32-partial extension (MODE 1)
constexpr int OFF_ZAP   = WS_BASE;                    // [11][64][4096]
constexpr int OFF_ZDP   = OFF_ZAP + NKA * NB * ZC;    // [16][64][4096]
constexpr long WS_FULL  = (long)OFF_ZDP + (long)NKD * NB * ZC;
// MFMA-mode extension (MODE 2)
constexpr long OFF_ZAP2 = WS_BASE;                    // [2][64][4096] f32
constexpr long OFF_ZDP2 = OFF_ZAP2 + 2 * NB * ZC;     // [2][64][4096] f32
constexpr long F_END    = OFF_ZDP2 + 2 * NB * ZC;     // 6,184,704 floats
// ushort region at (ushort*)(ws + F_END)
constexpr long U_WAT  = 0;                            // [256 n16][56 kb][512] bf16 frags
constexpr long U_WDT  = U_WAT + (long)4096 * KA;      // [256][80][512]
constexpr long U_X16A = U_WDT + (long)4096 * KD;      // [64][1792]
constexpr long U_X16D = U_X16A + (long)NB * KA;       // [64][2560]
constexpr long U_END  = U_X16D + (long)NB * KD;
constexpr long WS_MF_BYTES = F_END * 4 + U_END * 2;   // ~61 MB

constexpr long MEL_BASE   = 0;
constexpr long STOP_BASE  = (long)NB * NT * NMEL;
constexpr long ALIGN_BASE = STOP_BASE + (long)NB * NT;

typedef __attribute__((ext_vector_type(8))) short bf16x8;
typedef __attribute__((ext_vector_type(4))) float f32x4;

struct Params {
  const float *memory, *mel, *pw1, *pw2, *awx, *awh, *ab, *wq, *wm,
              *lconv, *wloc, *vatt, *dwx, *dwh, *db, *projw, *projb, *gatew, *gateb;
  float *out, *ws;
};

__device__ __forceinline__ float sigm(float x) { return 1.f / (1.f + __expf(-x)); }
__device__ __forceinline__ float tanh_t(float x) {
  x = fminf(fmaxf(x, -15.f), 15.f);
  const float a = __expf(2.f * x);
  return (a - 1.f) / (a + 1.f);
}
__device__ __forceinline__ unsigned short f2bf(float x) {  // RNE f32->bf16
  union { float f; unsigned u; } c; c.f = x;
  const unsigned r = c.u + 0x7FFFu + ((c.u >> 16) & 1u);
  return (unsigned short)(r >> 16);
}

// prenet stage 1: pm1 = relu(mel[:, tnext, :] @ pw1), 8 WGs, 8 b each
__device__ void do_s1(const Params& p, float* pm1, int tnext, int wl, int tid) {
  const int col = tid;
  for (int i = 0; i < 8; ++i) {
    const int b = wl * 8 + i;
    const float* mrow = p.mel + ((size_t)b * NT + tnext) * NMEL;
    float acc = 0.f;
    for (int k = 0; k < NMEL; ++k) acc += mrow[k] * p.pw1[k * NP + col];
    pm1[b * NP + col] = fmaxf(acc, 0.f);
  }
}

// prenet stage 2: relu(pm1 @ pw2) -> MODE2: bf16 x16_A[:, 0:256]; else f32 pdst
template<int MODE>
__device__ void do_s2(const Params& p, const float* pm1, float* pdst,
                      unsigned short* xA, int wl, int tid) {
  const int col = tid;
  for (int i = 0; i < 4; ++i) {
    const int b = wl * 4 + i;
    const float* pr = pm1 + b * NP;
    float acc = 0.f;
    for (int k = 0; k < NP; ++k) acc += pr[k] * p.pw2[k * NP + col];
    const float v = fmaxf(acc, 0.f);
    if constexpr (MODE == 2) xA[(size_t)b * KA + col] = f2bf(v);
    else                     pdst[b * NP + col] = v;
  }
}

template<int MODE>
__device__ void pre_a(const Params& p, float* sm, int wg, int tid) {
  float* ws = p.ws;
  const int gid = wg * 256 + tid;
  for (int i = gid; i < ZERO_CNT; i += G * 256) (ws + OFF_HA)[i] = 0.f;
  if constexpr (MODE == 0) {
    for (int i = gid; i < NB * ZC; i += G * 256) {
      ws[OFF_ZA + i] = p.ab[i & (ZC - 1)];
      ws[OFF_ZD + i] = p.db[i & (ZC - 1)];
    }
  }
  // fused conv kernel W2[k2][ad]
  for (int i = gid; i < 62 * NAD; i += G * 256) {
    const int k2 = i >> 7, ad = i & 127;
    float acc = 0.f;
    for (int f = 0; f < 32; ++f) acc += p.lconv[k2 * 32 + f] * p.wloc[f * NAD + ad];
    ws[OFF_W2 + i] = acc;
  }
  // keysT[b][ad][s]
  {
    const int b = wg >> 3, s0 = (wg & 7) * 32;
    const int sl = tid & 31, adg = tid >> 5;
    const float* mrow = p.memory + (size_t)(b * NS + s0 + sl) * NE;
    const float* wmb  = p.wm + adg * 16;
    float acc[16];
#pragma unroll
    for (int j = 0; j < 16; ++j) acc[j] = 0.f;
    for (int k = 0; k < NE; ++k) {
      const float mv = mrow[k];
      const float* wr = wmb + (size_t)k * NAD;
#pragma unroll
      for (int j = 0; j < 16; ++j) acc[j] += mv * wr[j];
    }
#pragma unroll
    for (int j = 0; j < 16; ++j)
      ws[OFF_KEYST + (b * NAD + adg * 16 + j) * NS + s0 + sl] = acc[j];
  }
  if constexpr (MODE == 2) {
    unsigned short* u16 = (unsigned short*)(ws + F_END);
    // zero x16_A / x16_D (covers ctx(-1)=h(-1)=h_d(-2)=0)
    for (long i = gid; i < (long)NB * KA + (long)NB * KD; i += (long)G * 256)
      u16[U_X16A + i] = 0;
    // pack bf16 weight fragments: tiles of 32k x 64n; A: 64x56, D: 64x80 tiles
    for (int tile = wg; tile < 3584 + 5120; tile += G) {
      const bool iA = tile < 3584;
      const int tt = iA ? tile : tile - 3584;
      const int NKB = iA ? 56 : 80;
      const int nt4 = tt / NKB, kb = tt % NKB;
      const int kx = iA ? 768 : 1536;
      const int r = tid >> 3, cg = (tid & 7) * 8;
      const int k = kb * 32 + r;
      const float* src = iA
          ? (k < kx ? p.awx + (size_t)k * ZC : p.awh + (size_t)(k - kx) * ZC)
          : (k < kx ? p.dwx + (size_t)k * ZC : p.dwh + (size_t)(k - kx) * ZC);
      const float* sp = src + nt4 * 64 + cg;
      const float4 v0 = *(const float4*)sp;
      const float4 v1 = *(const float4*)(sp + 4);
      __syncthreads();   // protect previous tile's readers
      *(float4*)(sm + r * 64 + cg)     = v0;
      *(float4*)(sm + r * 64 + cg + 4) = v1;
      __syncthreads();
      const int blk = tid >> 6, l = tid & 63;
      const int n16 = nt4 * 4 + blk;
      bf16x8 pk;
#pragma unroll
      for (int j = 0; j < 8; ++j)
        pk[j] = (short)f2bf(sm[((l >> 4) * 8 + j) * 64 + blk * 16 + (l & 15)]);
      unsigned short* dst = u16 + (iA ? U_WAT : U_WDT)
                          + ((size_t)(n16 * NKB + kb)) * 512 + l * 8;
      *(bf16x8*)dst = pk;
    }
  }
  if (wg >= 496 && wg < 504) do_s1(p, ws + OFF_PM1, 0, wg - 496, tid);
}

template<int MODE>
__device__ void pre_b(const Params& p, int wg, int tid) {
  if (wg >= 128 && wg < 144) {
    unsigned short* xA = (MODE == 2)
        ? (unsigned short*)(p.ws + F_END) + U_X16A : nullptr;
    do_s2<MODE>(p, p.ws + OFF_PM1, p.ws + OFF_P, xA, wg - 128, tid);
  }
}

// location features fl(t)[b][ad][s]
__device__ void do_fl(const Params& p, float* sm, int b, int tid) {
  float* ws = p.ws;
  float* chunk = sm;
  float* wp0 = sm + 4000;
  float* wp1 = sm + 4320;
  for (int i = tid; i < 288; i += 256) { wp0[i] = 0.f; wp1[i] = 0.f; }
  __syncthreads();
  wp0[15 + tid] = ws[OFF_WGL + b * NS + tid];
  wp1[15 + tid] = ws[OFF_WCU + b * NS + tid];
  __syncthreads();
  float x0[31], x1[31];
#pragma unroll
  for (int k = 0; k < 31; ++k) { x0[k] = wp0[tid + k]; x1[k] = wp1[tid + k]; }
  const float* kb = ws + OFF_KEYST + (b * NAD) * NS + tid;
  float* fb = ws + OFF_FL + (b * NAD) * NS + tid;
  const float* W2g = ws + OFF_W2;
  for (int ch = 0; ch < 2; ++ch) {
    for (int i = tid; i < 62 * 64; i += 256) {
      const int k2 = i >> 6, adl = i & 63;
      chunk[i] = W2g[k2 * NAD + ch * 64 + adl];
    }
    __syncthreads();
    for (int adl = 0; adl < 64; ++adl) {
      const int ad = ch * 64 + adl;
      float acc = kb[ad * NS];
#pragma unroll
      for (int k = 0; k < 31; ++k)
        acc = fmaf(x0[k], chunk[(2 * k) * 64 + adl],
              fmaf(x1[k], chunk[(2 * k + 1) * 64 + adl], acc));
      fb[ad * NS] = acc;
    }
    __syncthreads();
  }
}

template<int MODE>
__device__ void phase1(const Params& p, float* sm, int wg, int tid, int t) {
  float* ws = p.ws;
  if constexpr (MODE == 2) {
    unsigned short* u16 = (unsigned short*)(ws + F_END);
    if (wg < 256) {
      // MFMA GEMMs: A (wg<128): z_a(t) partials; D: z_d(t-1) partials
      const bool isA = wg < 128;
      if ((isA && t < NT) || (!isA && t >= 1)) {
        const int g   = isA ? wg : wg - 128;
        const int kc  = g & 1, nb4 = g >> 1;
        const int NKB = isA ? 56 : 80;
        const int nks = isA ? 28 : 40;
        const int kb0 = kc * nks;
        const int Kp  = isA ? KA : KD;
        const unsigned short* wT  = u16 + (isA ? U_WAT : U_WDT);
        const unsigned short* x16 = u16 + (isA ? U_X16A : U_X16D);
        float* zout = ws + (isA ? OFF_ZAP2 : OFF_ZDP2) + (size_t)kc * NB * ZC;
        const int l = tid & 63;
        const int n16 = nb4 * 4 + (tid >> 6);
        const unsigned short* wb = wT + ((size_t)(n16 * NKB + kb0)) * 512 + l * 8;
        const unsigned short* xb = x16 + (size_t)(l & 15) * Kp + kb0 * 32 + (l >> 4) * 8;
        f32x4 acc[4];
#pragma unroll
        for (int m = 0; m < 4; ++m) acc[m] = f32x4{0.f, 0.f, 0.f, 0.f};
#pragma unroll 2
        for (int ks = 0; ks < nks; ++ks) {
          const bf16x8 bfr = *(const bf16x8*)(wb + (size_t)ks * 512);
          const bf16x8 a0 = *(const bf16x8*)(xb + ks * 32);
          const bf16x8 a1 = *(const bf16x8*)(xb + ks * 32 + (size_t)16 * Kp);
          const bf16x8 a2 = *(const bf16x8*)(xb + ks * 32 + (size_t)32 * Kp);
          const bf16x8 a3 = *(const bf16x8*)(xb + ks * 32 + (size_t)48 * Kp);
          acc[0] = __builtin_amdgcn_mfma_f32_16x16x32_bf16(a0, bfr, acc[0], 0, 0, 0);
          acc[1] = __builtin_amdgcn_mfma_f32_16x16x32_bf16(a1, bfr, acc[1], 0, 0, 0);
          acc[2] = __builtin_amdgcn_mfma_f32_16x16x32_bf16(a2, bfr, acc[2], 0, 0, 0);
          acc[3] = __builtin_amdgcn_mfma_f32_16x16x32_bf16(a3, bfr, acc[3], 0, 0, 0);
        }
        const int ncol = n16 * 16 + (l & 15);
        const int rb = (l >> 4) * 4;
#pragma unroll
        for (int mb = 0; mb < 4; ++mb)
#pragma unroll
          for (int r = 0; r < 4; ++r)
            zout[(size_t)(mb * 16 + rb + r) * ZC + ncol] = acc[mb][r];
      }
    } else if (wg < 320) {
      if (t < NT) do_fl(p, sm, wg - 256, tid);
    } else if (wg < 328) {
      if (t + 1 < NT) do_s1(p, ws + OFF_PM1, t + 1, wg - 320, tid);
    }
    return;
  }
  // ---- legacy f32 paths (MODE 0/1) ----
  if (wg < 176) {
    if (t < NT) {
      const int cb = wg & 7, bs = (wg >> 3) & 1, kci = wg >> 4;
      const int col0 = cb * 512, b0 = bs * 32, k0 = kci * 163;
      const int kc = min(163, KA - k0);
      const float* pcur = ws + OFF_P + (t & 1) * (NB * NP);
      const float* ctxp = ws + OFF_CTX + ((t + 1) & 1) * (NB * NE);
      const float* h_a  = ws + OFF_HA;
      for (int bb = 0; bb < 32; ++bb) {
        const int b = b0 + bb;
        for (int kk = tid; kk < kc; kk += 256) {
          const int k = k0 + kk;
          float v;
          if (k < NP)           v = pcur[b * NP + k];
          else if (k < NP + NE) v = ctxp[b * NE + (k - NP)];
          else                  v = h_a[b * NA + (k - NP - NE)];
          sm[bb * 164 + kk] = v;
        }
      }
      __syncthreads();
      const int bgrp = tid >> 6, cgrp = tid & 63;
      const int c = col0 + cgrp * 8;
      float acc[8][8];
#pragma unroll
      for (int i = 0; i < 8; ++i)
#pragma unroll
        for (int j = 0; j < 8; ++j) acc[i][j] = 0.f;
      const float* sxb = sm + bgrp * 8 * 164;
#pragma unroll 2
      for (int kk = 0; kk < kc; ++kk) {
        const int k = k0 + kk;
        const float* wr = (k < 768) ? (p.awx + (size_t)k * ZC + c)
                                    : (p.awh + (size_t)(k - 768) * ZC + c);
        const float4 w0 = *(const float4*)wr;
        const float4 w1 = *(const float4*)(wr + 4);
#pragma unroll
        for (int i = 0; i < 8; ++i) {
          const float x = sxb[i * 164 + kk];
          acc[i][0] += x * w0.x; acc[i][1] += x * w0.y;
          acc[i][2] += x * w0.z; acc[i][3] += x * w0.w;
          acc[i][4] += x * w1.x; acc[i][5] += x * w1.y;
          acc[i][6] += x * w1.z; acc[i][7] += x * w1.w;
        }
      }
      if constexpr (MODE == 1) {
        float* zap = ws + OFF_ZAP;
#pragma unroll
        for (int i = 0; i < 8; ++i) {
          const int b = b0 + bgrp * 8 + i;
          float* dst = zap + (size_t)(kci * NB + b) * ZC + c;
          *(float4*)dst       = make_float4(acc[i][0], acc[i][1], acc[i][2], acc[i][3]);
          *(float4*)(dst + 4) = make_float4(acc[i][4], acc[i][5], acc[i][6], acc[i][7]);
        }
      } else {
        float* z_a = ws + OFF_ZA;
#pragma unroll
        for (int i = 0; i < 8; ++i) {
          const int b = b0 + bgrp * 8 + i;
#pragma unroll
          for (int j = 0; j < 8; ++j) atomicAdd(&z_a[b * ZC + c + j], acc[i][j]);
        }
      }
      __syncthreads();
    }
  } else if (wg < 432) {
    if (t >= 1) {
      const int lw = wg - 176;
      const int cb = lw & 7, bs = (lw >> 3) & 1, kci = lw >> 4;
      const int col0 = cb * 512, b0 = bs * 32, k0 = kci * 160;
      const int kc = 160;
      const float* ctxp = ws + OFF_CTX + ((t + 1) & 1) * (NB * NE);
      const float* h_a  = ws + OFF_HA;
      const float* h_d  = ws + OFF_HD;
      for (int bb = 0; bb < 32; ++bb) {
        const int b = b0 + bb;
        for (int kk = tid; kk < kc; kk += 256) {
          const int k = k0 + kk;
          float v;
          if (k < NA)           v = h_a[b * NA + k];
          else if (k < NA + NE) v = ctxp[b * NE + (k - NA)];
          else                  v = h_d[b * ND + (k - NA - NE)];
          sm[bb * 161 + kk] = v;
        }
      }
      __syncthreads();
      const int bgrp = tid >> 6, cgrp = tid & 63;
      const int c = col0 + cgrp * 8;
      float acc[8][8];
#pragma unroll
      for (int i = 0; i < 8; ++i)
#pragma unroll
        for (int j = 0; j < 8; ++j) acc[i][j] = 0.f;
      const float* sxb = sm + bgrp * 8 * 161;
#pragma unroll 2
      for (int kk = 0; kk < kc; ++kk) {
        const int k = k0 + kk;
        const float* wr = (k < 1536) ? (p.dwx + (size_t)k * ZC + c)
                                     : (p.dwh + (size_t)(k - 1536) * ZC + c);
        const float4 w0 = *(const float4*)wr;
        const float4 w1 = *(const float4*)(wr + 4);
#pragma unroll
        for (int i = 0; i < 8; ++i) {
          const float x = sxb[i * 161 + kk];
          acc[i][0] += x * w0.x; acc[i][1] += x * w0.y;
          acc[i][2] += x * w0.z; acc[i][3] += x * w0.w;
          acc[i][4] += x * w1.x; acc[i][5] += x * w1.y;
          acc[i][6] += x * w1.z; acc[i][7] += x * w1.w;
        }
      }
      if constexpr (MODE == 1) {
        float* zdp = ws + OFF_ZDP;
#pragma unroll
        for (int i = 0; i < 8; ++i) {
          const int b = b0 + bgrp * 8 + i;
          float* dst = zdp + (size_t)(kci * NB + b) * ZC + c;
          *(float4*)dst       = make_float4(acc[i][0], acc[i][1], acc[i][2], acc[i][3]);
          *(float4*)(dst + 4) = make_float4(acc[i][4], acc[i][5], acc[i][6], acc[i][7]);
        }
      } else {
        float* z_d = ws + OFF_ZD;
#pragma unroll
        for (int i = 0; i < 8; ++i) {
          const int b = b0 + bgrp * 8 + i;
#pragma unroll
          for (int j = 0; j < 8; ++j) atomicAdd(&z_d[b * ZC + c + j], acc[i][j]);
        }
      }
      __syncthreads();
    }
  } else if (wg < 496) {
    if (t < NT) do_fl(p, sm, wg - 432, tid);
  } else if (wg < 504) {
    if (t + 1 < NT) do_s1(p, ws + OFF_PM1, t + 1, wg - 496, tid);
  }
}

template<int MODE>
__device__ void phase2(const Params& p, float* sm, int wg, int tid, int t) {
  float* ws = p.ws;
  unsigned short* u16 = (MODE == 2) ? (unsigned short*)(ws + F_END) : nullptr;
  if (wg < 64) {
    // attention WG per b
    if (t < NT) {
      const int b = wg;
      float* h_sh = sm;
      float* q_sh = sm + 1024;
      float* red  = sm + 1152;
      float* w_sh = sm + 1408;
      float* c_a  = ws + OFF_CA;
      float* h_a  = ws + OFF_HA;
      unsigned short* xA = (MODE == 2) ? u16 + U_X16A + (size_t)b * KA : nullptr;
      unsigned short* xD = (MODE == 2) ? u16 + U_X16D + (size_t)b * KD : nullptr;
#pragma unroll
      for (int j = 0; j < 4; ++j) {
        const int g = tid + j * 256;
        float zi, zf, zg, zo;
        if constexpr (MODE == 2) {
          const float* za0 = ws + OFF_ZAP2 + (size_t)b * ZC;
          const float* za1 = za0 + (size_t)NB * ZC;
          zi = p.ab[g]        + za0[g]        + za1[g];
          zf = p.ab[1024 + g] + za0[1024 + g] + za1[1024 + g];
          zg = p.ab[2048 + g] + za0[2048 + g] + za1[2048 + g];
          zo = p.ab[3072 + g] + za0[3072 + g] + za1[3072 + g];
        } else if constexpr (MODE == 1) {
          zi = p.ab[g]; zf = p.ab[1024 + g]; zg = p.ab[2048 + g]; zo = p.ab[3072 + g];
          const float* zap = ws + OFF_ZAP + (size_t)b * ZC;
#pragma unroll 1
          for (int kci = 0; kci < NKA; ++kci) {
            const float* zp = zap + (size_t)kci * NB * ZC;
            zi += zp[g]; zf += zp[1024 + g]; zg += zp[2048 + g]; zo += zp[3072 + g];
          }
        } else {
          float* z_a = ws + OFF_ZA;
          zi = z_a[b * ZC + g];
          zf = z_a[b * ZC + 1024 + g];
          zg = z_a[b * ZC + 2048 + g];
          zo = z_a[b * ZC + 3072 + g];
          z_a[b * ZC + g]        = p.ab[g];
          z_a[b * ZC + 1024 + g] = p.ab[1024 + g];
          z_a[b * ZC + 2048 + g] = p.ab[2048 + g];
          z_a[b * ZC + 3072 + g] = p.ab[3072 + g];
        }
        const float cold = c_a[b * NA + g];
        const float iv = sigm(zi), fv = sigm(zf), gv = tanh_t(zg), ov = sigm(zo);
        const float c2 = fv * cold + iv * gv;
        const float h2 = ov * tanh_t(c2);
        c_a[b * NA + g] = c2;
        h_a[b * NA + g] = h2;
        h_sh[g] = h2;
        if constexpr (MODE == 2) {
          xA[768 + g] = f2bf(h2);   // A input h_a slot (next step)
          xD[g]       = f2bf(h2);   // D input h_a slot
        }
      }
      __syncthreads();
      // query = h_a(t) @ wq
      {
        const int ad = tid & 127, kh = tid >> 7;
        float acc = 0.f;
        const float* wqp = p.wq + ad;
        for (int k = kh * 512; k < kh * 512 + 512; ++k) acc += h_sh[k] * wqp[(size_t)k * NAD];
        red[tid] = acc;
      }
      __syncthreads();
      if (tid < 128) q_sh[tid] = red[tid] + red[tid + 128];
      __syncthreads();
      // energies
      float ev = 0.f;
      {
        const float* flp = ws + OFF_FL + (b * NAD) * NS + tid;
        for (int ad = 0; ad < NAD; ++ad)
          ev += tanh_t(q_sh[ad] + flp[ad * NS]) * p.vatt[ad];
      }
      red[tid] = ev; __syncthreads();
      for (int off = 128; off > 0; off >>= 1) {
        if (tid < off) red[tid] = fmaxf(red[tid], red[tid + off]);
        __syncthreads();
      }
      const float mx = red[0];
      __syncthreads();
      const float ex = __expf(ev - mx);
      red[tid] = ex; __syncthreads();
      for (int off = 128; off > 0; off >>= 1) {
        if (tid < off) red[tid] += red[tid + off];
        __syncthreads();
      }
      const float wv = ex / red[0];
      w_sh[tid] = wv;
      ws[OFF_WGL + b * NS + tid] = wv;
      ws[OFF_WCU + b * NS + tid] += wv;
      p.out[ALIGN_BASE + (size_t)b * NT * NS + (size_t)t * NS + tid] = wv;
      __syncthreads();
      // context
      {
        float a0 = 0.f, a1 = 0.f;
        const float* mb = p.memory + (size_t)b * NS * NE;
        for (int ss = 0; ss < NS; ++ss) {
          const float wcur = w_sh[ss];
          a0 += wcur * mb[ss * NE + tid];
          a1 += wcur * mb[ss * NE + tid + 256];
        }
        float* cdst = ws + OFF_CTX + (t & 1) * (NB * NE) + b * NE;
        cdst[tid] = a0;
        cdst[tid + 256] = a1;
        if constexpr (MODE == 2) {
          xA[256 + tid]  = f2bf(a0);
          xA[512 + tid]  = f2bf(a1);
          xD[1024 + tid] = f2bf(a0);
          xD[1280 + tid] = f2bf(a1);
        }
      }
    }
  } else if (wg < 128) {
    // decoder WG per b
    if (t >= 1) {
      const int b = wg - 64;
      const int tm1 = t - 1;
      float* h_sh = sm;
      float* red  = sm + 1024;
      float* c_d  = ws + OFF_CD;
      float* h_d  = ws + OFF_HD;
      unsigned short* xD = (MODE == 2) ? u16 + U_X16D + (size_t)b * KD : nullptr;
#pragma unroll
      for (int j = 0; j < 4; ++j) {
        const int g = tid + j * 256;
        float zi, zf, zg, zo;
        if constexpr (MODE == 2) {
          const float* zd0 = ws + OFF_ZDP2 + (size_t)b * ZC;
          const float* zd1 = zd0 + (size_t)NB * ZC;
          zi = p.db[g]        + zd0[g]        + zd1[g];
          zf = p.db[1024 + g] + zd0[1024 + g] + zd1[1024 + g];
          zg = p.db[2048 + g] + zd0[2048 + g] + zd1[2048 + g];
          zo = p.db[3072 + g] + zd0[3072 + g] + zd1[3072 + g];
        } else if constexpr (MODE == 1) {
          zi = p.db[g]; zf = p.db[1024 + g]; zg = p.db[2048 + g]; zo = p.db[3072 + g];
          const float* zdp = ws + OFF_ZDP + (size_t)b * ZC;
#pragma unroll 1
          for (int kci = 0; kci < NKD; ++kci) {
            const float* zp = zdp + (size_t)kci * NB * ZC;
            zi += zp[g]; zf += zp[1024 + g]; zg += zp[2048 + g]; zo += zp[3072 + g];
          }
        } else {
          float* z_d = ws + OFF_ZD;
          zi = z_d[b * ZC + g];
          zf = z_d[b * ZC + 1024 + g];
          zg = z_d[b * ZC + 2048 + g];
          zo = z_d[b * ZC + 3072 + g];
          z_d[b * ZC + g]        = p.db[g];
          z_d[b * ZC + 1024 + g] = p.db[1024 + g];
          z_d[b * ZC + 2048 + g] = p.db[2048 + g];
          z_d[b * ZC + 3072 + g] = p.db[3072 + g];
        }
        const float cold = c_d[b * ND + g];
        const float iv = sigm(zi), fv = sigm(zf), gv = tanh_t(zg), ov = sigm(zo);
        const float c2 = fv * cold + iv * gv;
        const float h2 = ov * tanh_t(c2);
        c_d[b * ND + g] = c2;
        h_d[b * ND + g] = h2;
        h_sh[g] = h2;
        if constexpr (MODE == 2) xD[1536 + g] = f2bf(h2);
      }
      __syncthreads();
      const float* ctxp = ws + OFF_CTX + (tm1 & 1) * (NB * NE) + b * NE;
      {
        float acc = 0.f;
        for (int k = tid; k < 1536; k += 256) {
          const float v = (k < 1024) ? h_sh[k] : ctxp[k - 1024];
          acc += v * p.gatew[k];
        }
        red[tid] = acc;
      }
      __syncthreads();
      for (int off = 128; off > 0; off >>= 1) {
        if (tid < off) red[tid] += red[tid + off];
        __syncthreads();
      }
      if (tid == 0) p.out[STOP_BASE + (size_t)b * NT + tm1] = sigm(red[0] + p.gateb[0]);
      __syncthreads();
      if (tid < 240) {
        const int m = tid % 80, kh = tid / 80;
        float acc = 0.f;
        for (int k = kh * 512; k < kh * 512 + 512; ++k) {
          const float v = (k < 1024) ? h_sh[k] : ctxp[k - 1024];
          acc += v * p.projw[(size_t)k * 80 + m];
        }
        red[kh * 80 + m] = acc;
      }
      __syncthreads();
      if (tid < 80) {
        const float mval = p.projb[tid] + red[tid] + red[80 + tid] + red[160 + tid];
        p.out[MEL_BASE + (size_t)b * NT * NMEL + (size_t)tm1 * NMEL + tid] = mval;
      }
    }
  } else if (wg < 144) {
    if (t + 1 < NT) {
      unsigned short* xA = (MODE == 2) ? u16 + U_X16A : nullptr;
      do_s2<MODE>(p, ws + OFF_PM1, ws + OFF_P + ((t + 1) & 1) * (NB * NP),
                  xA, wg - 128, tid);
    }
  }
}

template<int MODE>
__global__ __launch_bounds__(256, 2) void taco_coop(Params p) {
  cg::grid_group grid = cg::this_grid();
  const int wg  = blockIdx.x;
  const int tid = threadIdx.x;
  __shared__ float sm[SMN];

  pre_a<MODE>(p, sm, wg, tid);
  grid.sync();
  pre_b<MODE>(p, wg, tid);
  grid.sync();
  for (int t = 0; t <= NT; ++t) {
    phase1<MODE>(p, sm, wg, tid, t);
    grid.sync();
    phase2<MODE>(p, sm, wg, tid, t);
    grid.sync();
  }
}

// ---- non-cooperative fallback (atomic variant) ----
__global__ __launch_bounds__(256, 2) void k_pre_a(Params p) {
  __shared__ float sm[SMN];
  pre_a<0>(p, sm, blockIdx.x, threadIdx.x);
}
__global__ __launch_bounds__(256, 2) void k_pre_b(Params p) { pre_b<0>(p, blockIdx.x, threadIdx.x); }
__global__ __launch_bounds__(256, 2) void k_p1(Params p, int t) {
  __shared__ float sm[SMN];
  phase1<0>(p, sm, blockIdx.x, threadIdx.x, t);
}
__global__ __launch_bounds__(256, 2) void k_p2(Params p, int t) {
  __shared__ float sm[SMN];
  phase2<0>(p, sm, blockIdx.x, threadIdx.x, t);
}

extern "C" void kernel_launch(void* const* d_in, const int* in_sizes, int n_in,
                              void* d_out, int out_size, void* d_ws, size_t ws_size,
                              hipStream_t stream) {
  (void)in_sizes; (void)n_in; (void)out_size;
  Params prm;
  prm.memory = (const float*)d_in[0];
  prm.mel    = (const float*)d_in[1];
  prm.pw1    = (const float*)d_in[2];
  prm.pw2    = (const float*)d_in[3];
  prm.awx    = (const float*)d_in[4];
  prm.awh    = (const float*)d_in[5];
  prm.ab     = (const float*)d_in[6];
  prm.wq     = (const float*)d_in[7];
  prm.wm     = (const float*)d_in[8];
  prm.lconv  = (const float*)d_in[9];
  prm.wloc   = (const float*)d_in[10];
  prm.vatt   = (const float*)d_in[11];
  prm.dwx    = (const float*)d_in[12];
  prm.dwh    = (const float*)d_in[13];
  prm.db     = (const float*)d_in[14];
  prm.projw  = (const float*)d_in[15];
  prm.projb  = (const float*)d_in[16];
  prm.gatew  = (const float*)d_in[17];
  prm.gateb  = (const float*)d_in[18];
  prm.out = (float*)d_out;
  prm.ws  = (float*)d_ws;

  void* args[] = { &prm };
  hipError_t err;
  if (ws_size >= (size_t)WS_MF_BYTES) {
    err = hipLaunchCooperativeKernel((void*)taco_coop<2>, dim3(G), dim3(256), args, 0, stream);
  } else if (ws_size >= (size_t)WS_FULL * sizeof(float)) {
    err = hipLaunchCooperativeKernel((void*)taco_coop<1>, dim3(G), dim3(256), args, 0, stream);
  } else {
    err = hipLaunchCooperativeKernel((void*)taco_coop<0>, dim3(G), dim3(256), args, 0, stream);
  }
  if (err != hipSuccess) {
    k_pre_a<<<dim3(G), dim3(256), 0, stream>>>(prm);
    k_pre_b<<<dim3(G), dim3(256), 0, stream>>>(prm);
    for (int t = 0; t <= NT; ++t) {
      k_p1<<<dim3(G), dim3(256), 0, stream>>>(prm, t);
      k_p2<<<dim3(G), dim3(256), 0, stream>>>(prm, t);
    }
  }
}

// Round 5
// 176947.375 us; speedup vs baseline: 1.6715x; 1.2216x over previous
//
#include <hip/hip_runtime.h>
#include <hip/hip_cooperative_groups.h>

namespace cg = cooperative_groups;

constexpr int NB   = 64;     // batch
constexpr int NS   = 256;    // memory length S
constexpr int NT   = 500;    // time steps
constexpr int NMEL = 80;
constexpr int NE   = 512;    // memory dim E
constexpr int NP   = 256;    // prenet dim
constexpr int NA   = 1024;   // attention LSTM hidden
constexpr int ND   = 1024;   // decoder LSTM hidden
constexpr int NAD  = 128;    // attention dim
constexpr int ZC   = 4096;   // 4*hidden
constexpr int KA   = 1792;   // NP + NE + NA
constexpr int KD   = 2560;   // NA + NE + ND
constexpr int NKA  = 11;     // legacy f32 path A k-chunks
constexpr int NKD  = 16;     // legacy f32 path D k-chunks
constexpr int G    = 512;    // legacy grid blocks
constexpr int G2   = 256;    // MODE2 grid blocks (1/CU)

constexpr int SMN  = 5280;   // LDS floats (21.1 KB)

// ---- workspace layout (floats) ----
constexpr int OFF_KEYST = 0;                         // [64][128][256]
constexpr int OFF_FL    = OFF_KEYST + NB * NAD * NS; // [64][128][256]
constexpr int OFF_W2    = OFF_FL + NB * NAD * NS;    // [62][128]
constexpr int OFF_ZA    = OFF_W2 + 62 * NAD;         // atomic mode only
constexpr int OFF_ZD    = OFF_ZA + NB * ZC;          // atomic mode only
constexpr int OFF_HA    = OFF_ZD + NB * ZC;          // zero-block starts here
constexpr int OFF_CA    = OFF_HA + NB * NA;
constexpr int OFF_HD    = OFF_CA + NB * NA;
constexpr int OFF_CD    = OFF_HD + NB * ND;
constexpr int OFF_CTX   = OFF_CD + NB * ND;          // [2][64][512]
constexpr int OFF_WGL   = OFF_CTX + 2 * NB * NE;     // [64][256]
constexpr int OFF_WCU   = OFF_WGL + NB * NS;         // [64][256]
constexpr int OFF_P     = OFF_WCU + NB * NS;         // [2][64][256]
constexpr int OFF_PM1   = OFF_P + 2 * NB * NP;       // [64][256]
constexpr int WS_BASE   = OFF_PM1 + NB * NP;         // 5,136,128 floats
constexpr int ZERO_CNT  = OFF_P - OFF_HA;
// legacy f32-partial extension (MODE 1)
constexpr int OFF_ZAP   = WS_BASE;                    // [11][64][4096]
constexpr int OFF_ZDP   = OFF_ZAP + NKA * NB * ZC;    // [16][64][4096]
constexpr long WS_FULL  = (long)OFF_ZDP + (long)NKD * NB * ZC;
// MODE 2 extension
constexpr long OFF_ZA2  = WS_BASE;                    // [64][4096] f32
constexpr long OFF_ZD2  = OFF_ZA2 + NB * ZC;          // [64][4096] f32
constexpr long OFF_BAR  = OFF_ZD2 + NB * ZC;          // 512 uints barrier state
constexpr long F_END    = OFF_BAR + 512;
// ushort region at (ushort*)(ws + F_END)
constexpr long U_WAT  = 0;                            // [256 n16][56 kb][512] bf16
constexpr long U_WDT  = U_WAT + (long)4096 * KA;      // [256][80][512]
constexpr long U_X16A = U_WDT + (long)4096 * KD;      // [64][1792]
constexpr long U_X16D = U_X16A + (long)NB * KA;       // [64][2560]
constexpr long U_END  = U_X16D + (long)NB * KD;
constexpr long WS_MF_BYTES = F_END * 4 + U_END * 2;   // ~59 MB

constexpr long MEL_BASE   = 0;
constexpr long STOP_BASE  = (long)NB * NT * NMEL;
constexpr long ALIGN_BASE = STOP_BASE + (long)NB * NT;

typedef __attribute__((ext_vector_type(8))) short bf16x8;
typedef __attribute__((ext_vector_type(4))) float f32x4;

struct Params {
  const float *memory, *mel, *pw1, *pw2, *awx, *awh, *ab, *wq, *wm,
              *lconv, *wloc, *vatt, *dwx, *dwh, *db, *projw, *projb, *gatew, *gateb;
  float *out, *ws;
};

__device__ __forceinline__ float sigm(float x) { return 1.f / (1.f + __expf(-x)); }
__device__ __forceinline__ float tanh_t(float x) {
  x = fminf(fmaxf(x, -15.f), 15.f);
  const float a = __expf(2.f * x);
  return (a - 1.f) / (a + 1.f);
}
__device__ __forceinline__ unsigned short f2bf(float x) {  // RNE f32->bf16
  union { float f; unsigned u; } c; c.f = x;
  const unsigned r = c.u + 0x7FFFu + ((c.u >> 16) & 1u);
  return (unsigned short)(r >> 16);
}

// ---- fast grid barrier: 8 leaf counters (32 blocks each) + root + generation ----
// layout (uints, 128B apart): gen@0, root@32, leaf[i]@64+i*32
__device__ __forceinline__ void gbar(unsigned* bar, int wg, int tid) {
  __syncthreads();
  if (tid == 0) {
    unsigned* gen  = bar;
    unsigned* root = bar + 32;
    unsigned* leaf = bar + 64 + (wg >> 5) * 32;
    const unsigned g = __hip_atomic_load(gen, __ATOMIC_RELAXED, __HIP_MEMORY_SCOPE_AGENT);
    __threadfence();  // release prior writes (block-wide via preceding syncthreads)
    const unsigned lo = __hip_atomic_fetch_add(leaf, 1u, __ATOMIC_ACQ_REL,
                                               __HIP_MEMORY_SCOPE_AGENT);
    if (lo == 31) {
      __hip_atomic_store(leaf, 0u, __ATOMIC_RELAXED, __HIP_MEMORY_SCOPE_AGENT);
      const unsigned ro = __hip_atomic_fetch_add(root, 1u, __ATOMIC_ACQ_REL,
                                                 __HIP_MEMORY_SCOPE_AGENT);
      if (ro == 7) {
        __hip_atomic_store(root, 0u, __ATOMIC_RELAXED, __HIP_MEMORY_SCOPE_AGENT);
        __hip_atomic_fetch_add(gen, 1u, __ATOMIC_ACQ_REL, __HIP_MEMORY_SCOPE_AGENT);
      }
    }
    while (__hip_atomic_load(gen, __ATOMIC_RELAXED, __HIP_MEMORY_SCOPE_AGENT) == g)
      __builtin_amdgcn_s_sleep(32);
    __threadfence();  // acquire
  }
  __syncthreads();
}

// prenet stage 1
__device__ void do_s1(const Params& p, float* pm1, int tnext, int wl, int tid) {
  const int col = tid;
  for (int i = 0; i < 8; ++i) {
    const int b = wl * 8 + i;
    const float* mrow = p.mel + ((size_t)b * NT + tnext) * NMEL;
    float acc = 0.f;
    for (int k = 0; k < NMEL; ++k) acc += mrow[k] * p.pw1[k * NP + col];
    pm1[b * NP + col] = fmaxf(acc, 0.f);
  }
}

// prenet stage 2
template<int MODE>
__device__ void do_s2(const Params& p, const float* pm1, float* pdst,
                      unsigned short* xA, int wl, int tid) {
  const int col = tid;
  for (int i = 0; i < 4; ++i) {
    const int b = wl * 4 + i;
    const float* pr = pm1 + b * NP;
    float acc = 0.f;
    for (int k = 0; k < NP; ++k) acc += pr[k] * p.pw2[k * NP + col];
    const float v = fmaxf(acc, 0.f);
    if constexpr (MODE == 2) xA[(size_t)b * KA + col] = f2bf(v);
    else                     pdst[b * NP + col] = v;
  }
}

template<int MODE>
__device__ void pre_a(const Params& p, float* sm, int wg, int tid) {
  float* ws = p.ws;
  const int gid = wg * 256 + tid;
  const int gstr = gridDim.x * 256;
  for (int i = gid; i < ZERO_CNT; i += gstr) (ws + OFF_HA)[i] = 0.f;
  if constexpr (MODE == 0) {
    for (int i = gid; i < NB * ZC; i += gstr) {
      ws[OFF_ZA + i] = p.ab[i & (ZC - 1)];
      ws[OFF_ZD + i] = p.db[i & (ZC - 1)];
    }
  }
  if constexpr (MODE == 2) {
    if (wg == 0) for (int i = tid; i < 512; i += 256) ((unsigned*)(ws + OFF_BAR))[i] = 0;
  }
  // fused conv kernel W2[k2][ad]
  for (int i = gid; i < 62 * NAD; i += gstr) {
    const int k2 = i >> 7, ad = i & 127;
    float acc = 0.f;
    for (int f = 0; f < 32; ++f) acc += p.lconv[k2 * 32 + f] * p.wloc[f * NAD + ad];
    ws[OFF_W2 + i] = acc;
  }
  // keysT[b][ad][s]
  {
    const int nper = (MODE == 2) ? 4 : 8;          // WGs per b
    const int schunk = NS / nper;                  // s per WG
    const int b = wg / nper, si0 = (wg % nper) * schunk;
    const int sl = tid & 31, adg = tid >> 5;
    const float* wmb = p.wm + adg * 16;
    for (int so = 0; so < schunk; so += 32) {
      const float* mrow = p.memory + (size_t)(b * NS + si0 + so + sl) * NE;
      float acc[16];
#pragma unroll
      for (int j = 0; j < 16; ++j) acc[j] = 0.f;
      for (int k = 0; k < NE; ++k) {
        const float mv = mrow[k];
        const float* wr = wmb + (size_t)k * NAD;
#pragma unroll
        for (int j = 0; j < 16; ++j) acc[j] += mv * wr[j];
      }
#pragma unroll
      for (int j = 0; j < 16; ++j)
        ws[OFF_KEYST + (b * NAD + adg * 16 + j) * NS + si0 + so + sl] = acc[j];
    }
  }
  if constexpr (MODE == 2) {
    unsigned short* u16 = (unsigned short*)(ws + F_END);
    for (long i = gid; i < (long)NB * KA + (long)NB * KD; i += gstr)
      u16[U_X16A + i] = 0;
    // pack bf16 weight fragments: tiles of 32k x 64n
    for (int tile = wg; tile < 3584 + 5120; tile += gridDim.x) {
      const bool iA = tile < 3584;
      const int tt = iA ? tile : tile - 3584;
      const int NKB = iA ? 56 : 80;
      const int nt4 = tt / NKB, kb = tt % NKB;
      const int kx = iA ? 768 : 1536;
      const int r = tid >> 3, cgp = (tid & 7) * 8;
      const int k = kb * 32 + r;
      const float* src = iA
          ? (k < kx ? p.awx + (size_t)k * ZC : p.awh + (size_t)(k - kx) * ZC)
          : (k < kx ? p.dwx + (size_t)k * ZC : p.dwh + (size_t)(k - kx) * ZC);
      const float* sp = src + nt4 * 64 + cgp;
      const float4 v0 = *(const float4*)sp;
      const float4 v1 = *(const float4*)(sp + 4);
      __syncthreads();
      *(float4*)(sm + r * 64 + cgp)     = v0;
      *(float4*)(sm + r * 64 + cgp + 4) = v1;
      __syncthreads();
      const int blk = tid >> 6, l = tid & 63;
      const int n16 = nt4 * 4 + blk;
      bf16x8 pk;
#pragma unroll
      for (int j = 0; j < 8; ++j)
        pk[j] = (short)f2bf(sm[((l >> 4) * 8 + j) * 64 + blk * 16 + (l & 15)]);
      unsigned short* dst = u16 + (iA ? U_WAT : U_WDT)
                          + ((size_t)(n16 * NKB + kb)) * 512 + l * 8;
      *(bf16x8*)dst = pk;
    }
    if (wg >= 192 && wg < 200) do_s1(p, ws + OFF_PM1, 0, wg - 192, tid);
  } else {
    if (wg >= 496 && wg < 504) do_s1(p, ws + OFF_PM1, 0, wg - 496, tid);
  }
}

template<int MODE>
__device__ void pre_b(const Params& p, int wg, int tid) {
  if (wg >= 128 && wg < 144) {
    unsigned short* xA = (MODE == 2)
        ? (unsigned short*)(p.ws + F_END) + U_X16A : nullptr;
    do_s2<MODE>(p, p.ws + OFF_PM1, p.ws + OFF_P, xA, wg - 128, tid);
  }
}

// location features fl(t)[b][ad][s]
__device__ void do_fl(const Params& p, float* sm, int b, int tid) {
  float* ws = p.ws;
  float* chunk = sm;
  float* wp0 = sm + 4000;
  float* wp1 = sm + 4320;
  for (int i = tid; i < 288; i += 256) { wp0[i] = 0.f; wp1[i] = 0.f; }
  __syncthreads();
  wp0[15 + tid] = ws[OFF_WGL + b * NS + tid];
  wp1[15 + tid] = ws[OFF_WCU + b * NS + tid];
  __syncthreads();
  float x0[31], x1[31];
#pragma unroll
  for (int k = 0; k < 31; ++k) { x0[k] = wp0[tid + k]; x1[k] = wp1[tid + k]; }
  const float* kb = ws + OFF_KEYST + (b * NAD) * NS + tid;
  float* fb = ws + OFF_FL + (b * NAD) * NS + tid;
  const float* W2g = ws + OFF_W2;
  for (int ch = 0; ch < 2; ++ch) {
    for (int i = tid; i < 62 * 64; i += 256) {
      const int k2 = i >> 6, adl = i & 63;
      chunk[i] = W2g[k2 * NAD + ch * 64 + adl];
    }
    __syncthreads();
    for (int adl = 0; adl < 64; ++adl) {
      const int ad = ch * 64 + adl;
      float acc = kb[ad * NS];
#pragma unroll
      for (int k = 0; k < 31; ++k)
        acc = fmaf(x0[k], chunk[(2 * k) * 64 + adl],
              fmaf(x1[k], chunk[(2 * k + 1) * 64 + adl], acc));
      fb[ad * NS] = acc;
    }
    __syncthreads();
  }
}

template<int MODE>
__device__ void phase1(const Params& p, float* sm, int wg, int tid, int t) {
  float* ws = p.ws;
  if constexpr (MODE == 2) {
    unsigned short* u16 = (unsigned short*)(ws + F_END);
    if (wg < 128) {
      // MFMA GEMMs, full K per wave. A: wg<64 -> z_a(t); D: wg>=64 -> z_d(t-1)
      const bool isA = wg < 64;
      if ((isA && t < NT) || (!isA && t >= 1)) {
        const int g   = isA ? wg : wg - 64;
        const int NKB = isA ? 56 : 80;
        const int Kp  = isA ? KA : KD;
        const unsigned short* wT  = u16 + (isA ? U_WAT : U_WDT);
        const unsigned short* x16 = u16 + (isA ? U_X16A : U_X16D);
        float* zout = ws + (isA ? OFF_ZA2 : OFF_ZD2);
        const int l = tid & 63;
        const int n16 = g * 4 + (tid >> 6);
        const unsigned short* wb = wT + (size_t)n16 * NKB * 512 + l * 8;
        const unsigned short* xb = x16 + (size_t)(l & 15) * Kp + (l >> 4) * 8;
        f32x4 acc[4];
#pragma unroll
        for (int m = 0; m < 4; ++m) acc[m] = f32x4{0.f, 0.f, 0.f, 0.f};
#pragma unroll 2
        for (int ks = 0; ks < NKB; ++ks) {
          const bf16x8 bfr = *(const bf16x8*)(wb + (size_t)ks * 512);
          const bf16x8 a0 = *(const bf16x8*)(xb + ks * 32);
          const bf16x8 a1 = *(const bf16x8*)(xb + ks * 32 + (size_t)16 * Kp);
          const bf16x8 a2 = *(const bf16x8*)(xb + ks * 32 + (size_t)32 * Kp);
          const bf16x8 a3 = *(const bf16x8*)(xb + ks * 32 + (size_t)48 * Kp);
          acc[0] = __builtin_amdgcn_mfma_f32_16x16x32_bf16(a0, bfr, acc[0], 0, 0, 0);
          acc[1] = __builtin_amdgcn_mfma_f32_16x16x32_bf16(a1, bfr, acc[1], 0, 0, 0);
          acc[2] = __builtin_amdgcn_mfma_f32_16x16x32_bf16(a2, bfr, acc[2], 0, 0, 0);
          acc[3] = __builtin_amdgcn_mfma_f32_16x16x32_bf16(a3, bfr, acc[3], 0, 0, 0);
        }
        const int ncol = n16 * 16 + (l & 15);
        const int rb = (l >> 4) * 4;
#pragma unroll
        for (int mb = 0; mb < 4; ++mb)
#pragma unroll
          for (int r = 0; r < 4; ++r)
            zout[(size_t)(mb * 16 + rb + r) * ZC + ncol] = acc[mb][r];
      }
    } else if (wg < 192) {
      if (t < NT) do_fl(p, sm, wg - 128, tid);
    } else if (wg < 200) {
      if (t + 1 < NT) do_s1(p, ws + OFF_PM1, t + 1, wg - 192, tid);
    }
    return;
  }
  // ---- legacy f32 paths (MODE 0/1) ----
  if (wg < 176) {
    if (t < NT) {
      const int cb = wg & 7, bs = (wg >> 3) & 1, kci = wg >> 4;
      const int col0 = cb * 512, b0 = bs * 32, k0 = kci * 163;
      const int kc = min(163, KA - k0);
      const float* pcur = ws + OFF_P + (t & 1) * (NB * NP);
      const float* ctxp = ws + OFF_CTX + ((t + 1) & 1) * (NB * NE);
      const float* h_a  = ws + OFF_HA;
      for (int bb = 0; bb < 32; ++bb) {
        const int b = b0 + bb;
        for (int kk = tid; kk < kc; kk += 256) {
          const int k = k0 + kk;
          float v;
          if (k < NP)           v = pcur[b * NP + k];
          else if (k < NP + NE) v = ctxp[b * NE + (k - NP)];
          else                  v = h_a[b * NA + (k - NP - NE)];
          sm[bb * 164 + kk] = v;
        }
      }
      __syncthreads();
      const int bgrp = tid >> 6, cgrp = tid & 63;
      const int c = col0 + cgrp * 8;
      float acc[8][8];
#pragma unroll
      for (int i = 0; i < 8; ++i)
#pragma unroll
        for (int j = 0; j < 8; ++j) acc[i][j] = 0.f;
      const float* sxb = sm + bgrp * 8 * 164;
#pragma unroll 2
      for (int kk = 0; kk < kc; ++kk) {
        const int k = k0 + kk;
        const float* wr = (k < 768) ? (p.awx + (size_t)k * ZC + c)
                                    : (p.awh + (size_t)(k - 768) * ZC + c);
        const float4 w0 = *(const float4*)wr;
        const float4 w1 = *(const float4*)(wr + 4);
#pragma unroll
        for (int i = 0; i < 8; ++i) {
          const float x = sxb[i * 164 + kk];
          acc[i][0] += x * w0.x; acc[i][1] += x * w0.y;
          acc[i][2] += x * w0.z; acc[i][3] += x * w0.w;
          acc[i][4] += x * w1.x; acc[i][5] += x * w1.y;
          acc[i][6] += x * w1.z; acc[i][7] += x * w1.w;
        }
      }
      if constexpr (MODE == 1) {
        float* zap = ws + OFF_ZAP;
#pragma unroll
        for (int i = 0; i < 8; ++i) {
          const int b = b0 + bgrp * 8 + i;
          float* dst = zap + (size_t)(kci * NB + b) * ZC + c;
          *(float4*)dst       = make_float4(acc[i][0], acc[i][1], acc[i][2], acc[i][3]);
          *(float4*)(dst + 4) = make_float4(acc[i][4], acc[i][5], acc[i][6], acc[i][7]);
        }
      } else {
        float* z_a = ws + OFF_ZA;
#pragma unroll
        for (int i = 0; i < 8; ++i) {
          const int b = b0 + bgrp * 8 + i;
#pragma unroll
          for (int j = 0; j < 8; ++j) atomicAdd(&z_a[b * ZC + c + j], acc[i][j]);
        }
      }
      __syncthreads();
    }
  } else if (wg < 432) {
    if (t >= 1) {
      const int lw = wg - 176;
      const int cb = lw & 7, bs = (lw >> 3) & 1, kci = lw >> 4;
      const int col0 = cb * 512, b0 = bs * 32, k0 = kci * 160;
      const int kc = 160;
      const float* ctxp = ws + OFF_CTX + ((t + 1) & 1) * (NB * NE);
      const float* h_a  = ws + OFF_HA;
      const float* h_d  = ws + OFF_HD;
      for (int bb = 0; bb < 32; ++bb) {
        const int b = b0 + bb;
        for (int kk = tid; kk < kc; kk += 256) {
          const int k = k0 + kk;
          float v;
          if (k < NA)           v = h_a[b * NA + k];
          else if (k < NA + NE) v = ctxp[b * NE + (k - NA)];
          else                  v = h_d[b * ND + (k - NA - NE)];
          sm[bb * 161 + kk] = v;
        }
      }
      __syncthreads();
      const int bgrp = tid >> 6, cgrp = tid & 63;
      const int c = col0 + cgrp * 8;
      float acc[8][8];
#pragma unroll
      for (int i = 0; i < 8; ++i)
#pragma unroll
        for (int j = 0; j < 8; ++j) acc[i][j] = 0.f;
      const float* sxb = sm + bgrp * 8 * 161;
#pragma unroll 2
      for (int kk = 0; kk < kc; ++kk) {
        const int k = k0 + kk;
        const float* wr = (k < 1536) ? (p.dwx + (size_t)k * ZC + c)
                                     : (p.dwh + (size_t)(k - 1536) * ZC + c);
        const float4 w0 = *(const float4*)wr;
        const float4 w1 = *(const float4*)(wr + 4);
#pragma unroll
        for (int i = 0; i < 8; ++i) {
          const float x = sxb[i * 161 + kk];
          acc[i][0] += x * w0.x; acc[i][1] += x * w0.y;
          acc[i][2] += x * w0.z; acc[i][3] += x * w0.w;
          acc[i][4] += x * w1.x; acc[i][5] += x * w1.y;
          acc[i][6] += x * w1.z; acc[i][7] += x * w1.w;
        }
      }
      if constexpr (MODE == 1) {
        float* zdp = ws + OFF_ZDP;
#pragma unroll
        for (int i = 0; i < 8; ++i) {
          const int b = b0 + bgrp * 8 + i;
          float* dst = zdp + (size_t)(kci * NB + b) * ZC + c;
          *(float4*)dst       = make_float4(acc[i][0], acc[i][1], acc[i][2], acc[i][3]);
          *(float4*)(dst + 4) = make_float4(acc[i][4], acc[i][5], acc[i][6], acc[i][7]);
        }
      } else {
        float* z_d = ws + OFF_ZD;
#pragma unroll
        for (int i = 0; i < 8; ++i) {
          const int b = b0 + bgrp * 8 + i;
#pragma unroll
          for (int j = 0; j < 8; ++j) atomicAdd(&z_d[b * ZC + c + j], acc[i][j]);
        }
      }
      __syncthreads();
    }
  } else if (wg < 496) {
    if (t < NT) do_fl(p, sm, wg - 432, tid);
  } else if (wg < 504) {
    if (t + 1 < NT) do_s1(p, ws + OFF_PM1, t + 1, wg - 496, tid);
  }
}

template<int MODE>
__device__ void phase2(const Params& p, float* sm, int wg, int tid, int t) {
  float* ws = p.ws;
  unsigned short* u16 = (MODE == 2) ? (unsigned short*)(ws + F_END) : nullptr;
  if (wg < 64) {
    // attention WG per b
    if (t < NT) {
      const int b = wg;
      float* h_sh = sm;
      float* q_sh = sm + 1024;
      float* red  = sm + 1152;
      float* w_sh = sm + 1408;
      float* c_a  = ws + OFF_CA;
      float* h_a  = ws + OFF_HA;
      unsigned short* xA = (MODE == 2) ? u16 + U_X16A + (size_t)b * KA : nullptr;
      unsigned short* xD = (MODE == 2) ? u16 + U_X16D + (size_t)b * KD : nullptr;
#pragma unroll
      for (int j = 0; j < 4; ++j) {
        const int g = tid + j * 256;
        float zi, zf, zg, zo;
        if constexpr (MODE == 2) {
          const float* za0 = ws + OFF_ZA2 + (size_t)b * ZC;
          zi = p.ab[g]        + za0[g];
          zf = p.ab[1024 + g] + za0[1024 + g];
          zg = p.ab[2048 + g] + za0[2048 + g];
          zo = p.ab[3072 + g] + za0[3072 + g];
        } else if constexpr (MODE == 1) {
          zi = p.ab[g]; zf = p.ab[1024 + g]; zg = p.ab[2048 + g]; zo = p.ab[3072 + g];
          const float* zap = ws + OFF_ZAP + (size_t)b * ZC;
#pragma unroll 1
          for (int kci = 0; kci < NKA; ++kci) {
            const float* zp = zap + (size_t)kci * NB * ZC;
            zi += zp[g]; zf += zp[1024 + g]; zg += zp[2048 + g]; zo += zp[3072 + g];
          }
        } else {
          float* z_a = ws + OFF_ZA;
          zi = z_a[b * ZC + g];
          zf = z_a[b * ZC + 1024 + g];
          zg = z_a[b * ZC + 2048 + g];
          zo = z_a[b * ZC + 3072 + g];
          z_a[b * ZC + g]        = p.ab[g];
          z_a[b * ZC + 1024 + g] = p.ab[1024 + g];
          z_a[b * ZC + 2048 + g] = p.ab[2048 + g];
          z_a[b * ZC + 3072 + g] = p.ab[3072 + g];
        }
        const float cold = c_a[b * NA + g];
        const float iv = sigm(zi), fv = sigm(zf), gv = tanh_t(zg), ov = sigm(zo);
        const float c2 = fv * cold + iv * gv;
        const float h2 = ov * tanh_t(c2);
        c_a[b * NA + g] = c2;
        h_a[b * NA + g] = h2;
        h_sh[g] = h2;
        if constexpr (MODE == 2) {
          xA[768 + g] = f2bf(h2);
          xD[g]       = f2bf(h2);
        }
      }
      __syncthreads();
      // query = h_a(t) @ wq
      {
        const int ad = tid & 127, kh = tid >> 7;
        float acc = 0.f;
        const float* wqp = p.wq + ad;
        for (int k = kh * 512; k < kh * 512 + 512; ++k) acc += h_sh[k] * wqp[(size_t)k * NAD];
        red[tid] = acc;
      }
      __syncthreads();
      if (tid < 128) q_sh[tid] = red[tid] + red[tid + 128];
      __syncthreads();
      // energies
      float ev = 0.f;
      {
        const float* flp = ws + OFF_FL + (b * NAD) * NS + tid;
        for (int ad = 0; ad < NAD; ++ad)
          ev += tanh_t(q_sh[ad] + flp[ad * NS]) * p.vatt[ad];
      }
      red[tid] = ev; __syncthreads();
      for (int off = 128; off > 0; off >>= 1) {
        if (tid < off) red[tid] = fmaxf(red[tid], red[tid + off]);
        __syncthreads();
      }
      const float mx = red[0];
      __syncthreads();
      const float ex = __expf(ev - mx);
      red[tid] = ex; __syncthreads();
      for (int off = 128; off > 0; off >>= 1) {
        if (tid < off) red[tid] += red[tid + off];
        __syncthreads();
      }
      const float wv = ex / red[0];
      w_sh[tid] = wv;
      ws[OFF_WGL + b * NS + tid] = wv;
      ws[OFF_WCU + b * NS + tid] += wv;
      p.out[ALIGN_BASE + (size_t)b * NT * NS + (size_t)t * NS + tid] = wv;
      __syncthreads();
      // context
      {
        float a0 = 0.f, a1 = 0.f;
        const float* mb = p.memory + (size_t)b * NS * NE;
        for (int ss = 0; ss < NS; ++ss) {
          const float wcur = w_sh[ss];
          a0 += wcur * mb[ss * NE + tid];
          a1 += wcur * mb[ss * NE + tid + 256];
        }
        float* cdst = ws + OFF_CTX + (t & 1) * (NB * NE) + b * NE;
        cdst[tid] = a0;
        cdst[tid + 256] = a1;
        if constexpr (MODE == 2) {
          xA[256 + tid]  = f2bf(a0);
          xA[512 + tid]  = f2bf(a1);
          xD[1024 + tid] = f2bf(a0);
          xD[1280 + tid] = f2bf(a1);
        }
      }
    }
  } else if (wg < 128) {
    // decoder WG per b
    if (t >= 1) {
      const int b = wg - 64;
      const int tm1 = t - 1;
      float* h_sh = sm;
      float* red  = sm + 1024;
      float* c_d  = ws + OFF_CD;
      float* h_d  = ws + OFF_HD;
      unsigned short* xD = (MODE == 2) ? u16 + U_X16D + (size_t)b * KD : nullptr;
#pragma unroll
      for (int j = 0; j < 4; ++j) {
        const int g = tid + j * 256;
        float zi, zf, zg, zo;
        if constexpr (MODE == 2) {
          const float* zd0 = ws + OFF_ZD2 + (size_t)b * ZC;
          zi = p.db[g]        + zd0[g];
          zf = p.db[1024 + g] + zd0[1024 + g];
          zg = p.db[2048 + g] + zd0[2048 + g];
          zo = p.db[3072 + g] + zd0[3072 + g];
        } else if constexpr (MODE == 1) {
          zi = p.db[g]; zf = p.db[1024 + g]; zg = p.db[2048 + g]; zo = p.db[3072 + g];
          const float* zdp = ws + OFF_ZDP + (size_t)b * ZC;
#pragma unroll 1
          for (int kci = 0; kci < NKD; ++kci) {
            const float* zp = zdp + (size_t)kci * NB * ZC;
            zi += zp[g]; zf += zp[1024 + g]; zg += zp[2048 + g]; zo += zp[3072 + g];
          }
        } else {
          float* z_d = ws + OFF_ZD;
          zi = z_d[b * ZC + g];
          zf = z_d[b * ZC + 1024 + g];
          zg = z_d[b * ZC + 2048 + g];
          zo = z_d[b * ZC + 3072 + g];
          z_d[b * ZC + g]        = p.db[g];
          z_d[b * ZC + 1024 + g] = p.db[1024 + g];
          z_d[b * ZC + 2048 + g] = p.db[2048 + g];
          z_d[b * ZC + 3072 + g] = p.db[3072 + g];
        }
        const float cold = c_d[b * ND + g];
        const float iv = sigm(zi), fv = sigm(zf), gv = tanh_t(zg), ov = sigm(zo);
        const float c2 = fv * cold + iv * gv;
        const float h2 = ov * tanh_t(c2);
        c_d[b * ND + g] = c2;
        h_d[b * ND + g] = h2;
        h_sh[g] = h2;
        if constexpr (MODE == 2) xD[1536 + g] = f2bf(h2);
      }
      __syncthreads();
      const float* ctxp = ws + OFF_CTX + (tm1 & 1) * (NB * NE) + b * NE;
      {
        float acc = 0.f;
        for (int k = tid; k < 1536; k += 256) {
          const float v = (k < 1024) ? h_sh[k] : ctxp[k - 1024];
          acc += v * p.gatew[k];
        }
        red[tid] = acc;
      }
      __syncthreads();
      for (int off = 128; off > 0; off >>= 1) {
        if (tid < off) red[tid] += red[tid + off];
        __syncthreads();
      }
      if (tid == 0) p.out[STOP_BASE + (size_t)b * NT + tm1] = sigm(red[0] + p.gateb[0]);
      __syncthreads();
      if (tid < 240) {
        const int m = tid % 80, kh = tid / 80;
        float acc = 0.f;
        for (int k = kh * 512; k < kh * 512 + 512; ++k) {
          const float v = (k < 1024) ? h_sh[k] : ctxp[k - 1024];
          acc += v * p.projw[(size_t)k * 80 + m];
        }
        red[kh * 80 + m] = acc;
      }
      __syncthreads();
      if (tid < 80) {
        const float mval = p.projb[tid] + red[tid] + red[80 + tid] + red[160 + tid];
        p.out[MEL_BASE + (size_t)b * NT * NMEL + (size_t)tm1 * NMEL + tid] = mval;
      }
    }
  } else if (wg < 144) {
    if (t + 1 < NT) {
      unsigned short* xA = (MODE == 2) ? u16 + U_X16A : nullptr;
      do_s2<MODE>(p, ws + OFF_PM1, ws + OFF_P + ((t + 1) & 1) * (NB * NP),
                  xA, wg - 128, tid);
    }
  }
}

template<int MODE>
__global__ __launch_bounds__(256, 2) void taco_coop(Params p) {
  cg::grid_group grid = cg::this_grid();
  const int wg  = blockIdx.x;
  const int tid = threadIdx.x;
  __shared__ float sm[SMN];

  pre_a<MODE>(p, sm, wg, tid);
  grid.sync();
  pre_b<MODE>(p, wg, tid);
  grid.sync();
  if constexpr (MODE == 2) {
    unsigned* bar = (unsigned*)(p.ws + OFF_BAR);
    for (int t = 0; t <= NT; ++t) {
      phase1<MODE>(p, sm, wg, tid, t);
      gbar(bar, wg, tid);
      phase2<MODE>(p, sm, wg, tid, t);
      gbar(bar, wg, tid);
    }
  } else {
    for (int t = 0; t <= NT; ++t) {
      phase1<MODE>(p, sm, wg, tid, t);
      grid.sync();
      phase2<MODE>(p, sm, wg, tid, t);
      grid.sync();
    }
  }
}

// ---- non-cooperative fallback (atomic variant) ----
__global__ __launch_bounds__(256, 2) void k_pre_a(Params p) {
  __shared__ float sm[SMN];
  pre_a<0>(p, sm, blockIdx.x, threadIdx.x);
}
__global__ __launch_bounds__(256, 2) void k_pre_b(Params p) { pre_b<0>(p, blockIdx.x, threadIdx.x); }
__global__ __launch_bounds__(256, 2) void k_p1(Params p, int t) {
  __shared__ float sm[SMN];
  phase1<0>(p, sm, blockIdx.x, threadIdx.x, t);
}
__global__ __launch_bounds__(256, 2) void k_p2(Params p, int t) {
  __shared__ float sm[SMN];
  phase2<0>(p, sm, blockIdx.x, threadIdx.x, t);
}

extern "C" void kernel_launch(void* const* d_in, const int* in_sizes, int n_in,
                              void* d_out, int out_size, void* d_ws, size_t ws_size,
                              hipStream_t stream) {
  (void)in_sizes; (void)n_in; (void)out_size;
  Params prm;
  prm.memory = (const float*)d_in[0];
  prm.mel    = (const float*)d_in[1];
  prm.pw1    = (const float*)d_in[2];
  prm.pw2    = (const float*)d_in[3];
  prm.awx    = (const float*)d_in[4];
  prm.awh    = (const float*)d_in[5];
  prm.ab     = (const float*)d_in[6];
  prm.wq     = (const float*)d_in[7];
  prm.wm     = (const float*)d_in[8];
  prm.lconv  = (const float*)d_in[9];
  prm.wloc   = (const float*)d_in[10];
  prm.vatt   = (const float*)d_in[11];
  prm.dwx    = (const float*)d_in[12];
  prm.dwh    = (const float*)d_in[13];
  prm.db     = (const float*)d_in[14];
  prm.projw  = (const float*)d_in[15];
  prm.projb  = (const float*)d_in[16];
  prm.gatew  = (const float*)d_in[17];
  prm.gateb  = (const float*)d_in[18];
  prm.out = (float*)d_out;
  prm.ws  = (float*)d_ws;

  void* args[] = { &prm };
  hipError_t err;
  if (ws_size >= (size_t)WS_MF_BYTES) {
    err = hipLaunchCooperativeKernel((void*)taco_coop<2>, dim3(G2), dim3(256), args, 0, stream);
  } else if (ws_size >= (size_t)WS_FULL * sizeof(float)) {
    err = hipLaunchCooperativeKernel((void*)taco_coop<1>, dim3(G), dim3(256), args, 0, stream);
  } else {
    err = hipLaunchCooperativeKernel((void*)taco_coop<0>, dim3(G), dim3(256), args, 0, stream);
  }
  if (err != hipSuccess) {
    k_pre_a<<<dim3(G), dim3(256), 0, stream>>>(prm);
    k_pre_b<<<dim3(G), dim3(256), 0, stream>>>(prm);
    for (int t = 0; t <= NT; ++t) {
      k_p1<<<dim3(G), dim3(256), 0, stream>>>(prm, t);
      k_p2<<<dim3(G), dim3(256), 0, stream>>>(prm, t);
    }
  }
}